// Round 14
// baseline (321.896 us; speedup 1.0000x reference)
//
#include <hip/hip_runtime.h>
#include <math.h>

constexpr int NN = 100000;
constexpr int NE = 1600000;
constexpr int NG = 512;
constexpr int NBKT = (NN + 127) / 128;   // 782 dst-buckets (128 nodes each)
constexpr int BSTR = 2560;               // fixed bucket capacity (mean 2048, sd 45 -> 11 sigma)
constexpr int PADREG = BSTR + 896;       // padded csr region per bucket
constexpr int BCAP = 3072;               // LDS staging capacity
constexpr int NT1 = (NN + 63) / 64;      // 1563 gemm1 tiles

typedef unsigned short bf16_t;
typedef unsigned int u32x4 __attribute__((ext_vector_type(4)));   // nontemporal-store-able
__device__ __forceinline__ bf16_t f2bf(float f) {
    unsigned u = __float_as_uint(f);
    unsigned r = (u + 0x7fffu + ((u >> 16) & 1u)) >> 16;   // round-nearest-even
    return (bf16_t)r;
}
__device__ __forceinline__ float bflo(unsigned u) { return __uint_as_float(u << 16); }
__device__ __forceinline__ float bfhi(unsigned u) { return __uint_as_float(u & 0xffff0000u); }
__device__ __forceinline__ unsigned bfpack(float lo, float hi) {
    return ((unsigned)f2bf(hi) << 16) | (unsigned)f2bf(lo);
}
__device__ __forceinline__ float eluf(float x) {
    return x > 0.f ? x : expm1f(x);
}

// LDS-aggregated bucket scatter (R8-verified): 512 blocks x 1024 threads.
// R14: counting pass ALSO accumulates global per-node degree (degg) via
// fire-and-forget atomics (~1.6M spread over 100k addresses, hidden under
// this kernel's huge latency slack at 1.6% VALUBusy). This feeds gemm1's
// dinv directly and deletes R13's redundant per-block bucket scans.
__global__ __launch_bounds__(1024) void k_scatter_bkt(const int* __restrict__ src,
                                                      const int* __restrict__ dst,
                                                      int* __restrict__ bktCur,
                                                      int* __restrict__ ebuf,
                                                      int* __restrict__ degg) {
    __shared__ int cnt[NBKT];
    __shared__ int base[NBKT];
    int tid = threadIdx.x;
    for (int i = tid; i < NBKT; i += 1024) cnt[i] = 0;
    __syncthreads();
    int per = (NE + gridDim.x - 1) / gridDim.x;
    int e0 = blockIdx.x * per;
    int e1 = min(e0 + per, NE);
    for (int e = e0 + tid; e < e1; e += 1024) {
        int d = __builtin_nontemporal_load(dst + e);
        atomicAdd(&cnt[d >> 7], 1);
        atomicAdd(&degg[d], 1);                   // global per-node degree
    }
    __syncthreads();
    for (int i = tid; i < NBKT; i += 1024) {
        int c = cnt[i];
        base[i] = i * BSTR + (c ? atomicAdd(&bktCur[i], c) : 0);
        cnt[i] = 0;                 // reuse as local cursor
    }
    __syncthreads();
    for (int e = e0 + tid; e < e1; e += 1024) {
        int s = __builtin_nontemporal_load(src + e);
        int d = __builtin_nontemporal_load(dst + e);
        int b = d >> 7;
        int off = atomicAdd(&cnt[b], 1);
        ebuf[base[b] + off] = (s << 7) | (d & 127);
    }
}

// R13/R14 FUSED heterogeneous kernel: blocks [0,NT1) run the gemm1 tile;
// blocks [NT1, NT1+NBKT] run bktsort (+gptr at the end). R14: gemm1's dinv
// now reads precomputed degg (broadcast loads) -- the R13 per-block bucket
// scan (12.8MB redundant reads + 3.2M LDS atomics, 485K conflicts) deleted.
__global__ __launch_bounds__(256) void k_sort_gemm1(const int* __restrict__ bktCur,
                                                    const int* __restrict__ ebuf,
                                                    int* __restrict__ csr,
                                                    int2* __restrict__ rowInfo,
                                                    float* __restrict__ dinv,
                                                    const int* __restrict__ batch,
                                                    int* __restrict__ gptr,
                                                    const float* __restrict__ x,
                                                    const float* __restrict__ W1,
                                                    bf16_t* __restrict__ y1b,
                                                    const int* __restrict__ degg) {
    __shared__ __align__(16) unsigned smem_u[8576];   // 34.3 KB union
    int tid = threadIdx.x;
    if (blockIdx.x < NT1) {
        // ---------------- gemm1 role (R5-verified core) ----------------
        float* sx = (float*)smem_u;                   // [64*68]
        float* sw = sx + 64 * 68;                     // [66*64]
        for (int i = tid; i < 66 * 32; i += 256) ((float2*)sw)[i] = ((const float2*)W1)[i];
        int base = blockIdx.x * 64;
        int rows = min(64, NN - base);
        int cnt2v = rows * 33;
        const float2* xp = (const float2*)(x + base * 66);
        for (int i = tid; i < cnt2v; i += 256) {
            int r = i / 33, kk = i - r * 33;
            ((float2*)(sx + r * 68))[kk] = xp[i];
        }
        __syncthreads();
        int tr = tid >> 4, tc = tid & 15;             // 16 row-groups x 16 col-groups
        const float* sxr = sx + tr * 4 * 68;
        const float* swc = sw + tc * 4;
        float acc[4][4];
#pragma unroll
        for (int r = 0; r < 4; ++r)
#pragma unroll
            for (int c = 0; c < 4; ++c) acc[r][c] = 0.f;
#pragma unroll 4
        for (int ks = 0; ks < 64; ks += 4) {
            float4 a0 = *(const float4*)(sxr + 0 * 68 + ks);
            float4 a1 = *(const float4*)(sxr + 1 * 68 + ks);
            float4 a2 = *(const float4*)(sxr + 2 * 68 + ks);
            float4 a3 = *(const float4*)(sxr + 3 * 68 + ks);
            float4 b0 = *(const float4*)(swc + (ks + 0) * 64);
            float4 b1 = *(const float4*)(swc + (ks + 1) * 64);
            float4 b2 = *(const float4*)(swc + (ks + 2) * 64);
            float4 b3 = *(const float4*)(swc + (ks + 3) * 64);
#define FMA4(ar, bv) do { \
            acc[0][0] = fmaf(a0.ar, bv.x, acc[0][0]); acc[0][1] = fmaf(a0.ar, bv.y, acc[0][1]); \
            acc[0][2] = fmaf(a0.ar, bv.z, acc[0][2]); acc[0][3] = fmaf(a0.ar, bv.w, acc[0][3]); \
            acc[1][0] = fmaf(a1.ar, bv.x, acc[1][0]); acc[1][1] = fmaf(a1.ar, bv.y, acc[1][1]); \
            acc[1][2] = fmaf(a1.ar, bv.z, acc[1][2]); acc[1][3] = fmaf(a1.ar, bv.w, acc[1][3]); \
            acc[2][0] = fmaf(a2.ar, bv.x, acc[2][0]); acc[2][1] = fmaf(a2.ar, bv.y, acc[2][1]); \
            acc[2][2] = fmaf(a2.ar, bv.z, acc[2][2]); acc[2][3] = fmaf(a2.ar, bv.w, acc[2][3]); \
            acc[3][0] = fmaf(a3.ar, bv.x, acc[3][0]); acc[3][1] = fmaf(a3.ar, bv.y, acc[3][1]); \
            acc[3][2] = fmaf(a3.ar, bv.z, acc[3][2]); acc[3][3] = fmaf(a3.ar, bv.w, acc[3][3]); } while (0)
            FMA4(x, b0); FMA4(y, b1); FMA4(z, b2); FMA4(w, b3);
#undef FMA4
        }
        // k tail: 64, 65
#pragma unroll
        for (int k = 64; k < 66; ++k) {
            float4 bt = *(const float4*)(swc + k * 64);
#pragma unroll
            for (int r = 0; r < 4; ++r) {
                float av = sxr[r * 68 + k];
                acc[r][0] = fmaf(av, bt.x, acc[r][0]);
                acc[r][1] = fmaf(av, bt.y, acc[r][1]);
                acc[r][2] = fmaf(av, bt.z, acc[r][2]);
                acc[r][3] = fmaf(av, bt.w, acc[r][3]);
            }
        }
        // epilogue: cols tc*4..tc*4+3 all in slice tc>>2, lanes (tc&3)*4..+3
        bf16_t* dstp = y1b + (tc >> 2) * ((NN + 1) * 16) + (tc & 3) * 4;
#pragma unroll
        for (int r = 0; r < 4; ++r) {
            int nn = base + tr * 4 + r;
            if (nn < NN) {
                float di = rsqrtf((float)degg[nn] + 1.0f);   // bit-identical to bktsort dinv
                ushort4 o;
                o.x = f2bf(di * acc[r][0]); o.y = f2bf(di * acc[r][1]);
                o.z = f2bf(di * acc[r][2]); o.w = f2bf(di * acc[r][3]);
                *(ushort4*)(dstp + (size_t)nn * 16) = o;
            } else if (nn == NN) {
                ushort4 o; o.x = 0; o.y = 0; o.z = 0; o.w = 0;
                *(ushort4*)(dstp + (size_t)nn * 16) = o;   // sentinel zero row
            }
        }
        return;
    }
    // ---------------- bktsort role (R8-verified) ----------------
    int b = blockIdx.x - NT1;
    if (b == NBKT) {                                  // gptr block
        for (int g = tid; g <= NG; g += 256) {
            if (g == NG) { gptr[NG] = NN; continue; }
            int lo = 0, hi = NN;
            while (lo < hi) {
                int mid = (lo + hi) >> 1;
                if (batch[mid] < g) lo = mid + 1; else hi = mid;
            }
            gptr[g] = lo;
        }
        return;
    }
    int* sbuf = (int*)smem_u;                         // [BCAP]
    int* cnt  = sbuf + BCAP;                          // [128]
    int* scn  = cnt + 128;                            // [128]
    int* cur  = scn + 128;                            // [128]
    int* padTotS = cur + 128;                         // [1]
    int base = b * BSTR;
    int n = min(bktCur[b], BSTR);
    int pbase = b * PADREG;                           // 8-aligned (PADREG % 8 == 0)
    for (int i = tid; i < n; i += 256) sbuf[i] = __builtin_nontemporal_load(ebuf + base + i);
    if (tid < 128) cnt[tid] = 0;
    __syncthreads();
    for (int i = tid; i < n; i += 256) atomicAdd(&cnt[sbuf[i] & 127], 1);
    __syncthreads();
    int deg = (tid < 128) ? cnt[tid] : 0;
    int pcnt = (deg + 7) & ~7;
    if (tid < 128) scn[tid] = pcnt;
    __syncthreads();
    for (int off = 1; off < 128; off <<= 1) {
        int t = (tid < 128 && tid >= off) ? scn[tid - off] : 0;
        __syncthreads();
        if (tid < 128) scn[tid] += t;
        __syncthreads();
    }
    if (tid == 127) *padTotS = scn[127];
    if (tid < 128) {
        int ex = scn[tid] - pcnt;
        cur[tid] = ex;
        int node = b * 128 + tid;
        if (node < NN) {
            rowInfo[node] = make_int2(pbase + ex, pbase + ex + pcnt);
            dinv[node] = rsqrtf((float)deg + 1.0f);
        }
    }
    __syncthreads();
    int padTot = *padTotS;
    for (int i = tid; i < padTot; i += 256) csr[pbase + i] = NN;   // sentinel fill
    __syncthreads();
    for (int i = tid; i < n; i += 256) {
        int p = sbuf[i];
        int pos = atomicAdd(&cur[p & 127], 1);
        csr[pbase + pos] = p >> 7;
    }
}

// Slice-blocked CSR gather (R8-verified form). 32B rows, 4 slices L2-fit;
// 2-lane groups, 16B uint4 per lane; csr cacheable + one-round-ahead
// prefetch younger than y loads.
template<int NSL>   // 4 for C=64, 2 for C=32
__global__ __launch_bounds__(256) void k_gather(const int2* __restrict__ rowInfo,
                                                const int* __restrict__ csr,
                                                const float* __restrict__ dinv,
                                                const uint4* __restrict__ yb,
                                                uint4* __restrict__ aggb,
                                                float* __restrict__ sums,
                                                float* __restrict__ sqs) {
    constexpr int SH = (NSL == 4) ? 2 : 1;
    __shared__ float sSum[16], sSq[16];
    int tid = threadIdx.x;
    if (tid < 16) { sSum[tid] = 0.f; sSq[tid] = 0.f; }
    __syncthreads();
    int slice = blockIdx.x & (NSL - 1);
    int part = blockIdx.x >> SH;
    int nparts = gridDim.x >> SH;
    int lane = tid & 1;                           // half-row selector
    int grp = tid >> 1;                           // 128 node-groups per block
    const uint4* y = yb + (size_t)slice * ((NN + 1) * 2) + lane;
    uint4* agg = aggb + (size_t)slice * (NN * 2) + lane;
    float s[8], q[8];
#pragma unroll
    for (int k = 0; k < 8; ++k) { s[k] = 0.f; q[k] = 0.f; }
    for (int n = part * 128 + grp; n < NN; n += nparts * 128) {
        int2 ri = rowInfo[n];
        float a[8];
#pragma unroll
        for (int k = 0; k < 8; ++k) a[k] = 0.f;
        int j = ri.x;
        unsigned long long c0 = 0, c1 = 0, c2 = 0, c3 = 0;
        if (j < ri.y) {                            // prime the csr pipeline
            const unsigned long long* cp = (const unsigned long long*)(csr + j);
            c0 = cp[0]; c1 = cp[1]; c2 = cp[2]; c3 = cp[3];
        }
        while (j < ri.y) {
            int i0 = (int)(c0 & 0xffffffffu), i1 = (int)(c0 >> 32);
            int i2 = (int)(c1 & 0xffffffffu), i3 = (int)(c1 >> 32);
            int i4 = (int)(c2 & 0xffffffffu), i5 = (int)(c2 >> 32);
            int i6 = (int)(c3 & 0xffffffffu), i7 = (int)(c3 >> 32);
            j += 8;
            uint4 v0 = y[i0 * 2];
            uint4 v1 = y[i1 * 2];
            uint4 v2 = y[i2 * 2];
            uint4 v3 = y[i3 * 2];
            uint4 v4 = y[i4 * 2];
            uint4 v5 = y[i5 * 2];
            uint4 v6 = y[i6 * 2];
            uint4 v7 = y[i7 * 2];
            if (j < ri.y) {                        // prefetch next round (younger than y)
                const unsigned long long* np = (const unsigned long long*)(csr + j);
                c0 = np[0]; c1 = np[1]; c2 = np[2]; c3 = np[3];
            }
#define ACC8(v) do { \
            a[0] += bflo((v).x); a[1] += bfhi((v).x); \
            a[2] += bflo((v).y); a[3] += bfhi((v).y); \
            a[4] += bflo((v).z); a[5] += bfhi((v).z); \
            a[6] += bflo((v).w); a[7] += bfhi((v).w); } while (0)
            ACC8(v0); ACC8(v1); ACC8(v2); ACC8(v3);
            ACC8(v4); ACC8(v5); ACC8(v6); ACC8(v7);
#undef ACC8
        }
        uint4 vs = y[n * 2];                      // self loop
        float di = dinv[n];
        a[0] = di * (a[0] + bflo(vs.x)); a[1] = di * (a[1] + bfhi(vs.x));
        a[2] = di * (a[2] + bflo(vs.y)); a[3] = di * (a[3] + bfhi(vs.y));
        a[4] = di * (a[4] + bflo(vs.z)); a[5] = di * (a[5] + bfhi(vs.z));
        a[6] = di * (a[6] + bflo(vs.w)); a[7] = di * (a[7] + bfhi(vs.w));
        u32x4 o;
        o.x = bfpack(a[0], a[1]); o.y = bfpack(a[2], a[3]);
        o.z = bfpack(a[4], a[5]); o.w = bfpack(a[6], a[7]);
        __builtin_nontemporal_store(o, (u32x4*)(agg + n * 2));
#pragma unroll
        for (int k = 0; k < 8; ++k) {
            float av = (k == 0) ? a[0] : (k == 1) ? a[1] : (k == 2) ? a[2] : (k == 3) ? a[3]
                     : (k == 4) ? a[4] : (k == 5) ? a[5] : (k == 6) ? a[6] : a[7];
            s[k] += av; q[k] += av * av;
        }
    }
    // wave shuffle-tree over the 32 group-pairs (keeps lane parity separate),
    // then 2 threads/wave commit to LDS (64 LDS atomics/block, was 2048).
#pragma unroll
    for (int k = 0; k < 8; ++k) {
        float sv = s[k], qv = q[k];
#pragma unroll
        for (int off = 2; off < 64; off <<= 1) {
            sv += __shfl_xor(sv, off);
            qv += __shfl_xor(qv, off);
        }
        if ((tid & 63) < 2) {
            atomicAdd(&sSum[lane * 8 + k], sv);
            atomicAdd(&sSq[lane * 8 + k], qv);
        }
    }
    __syncthreads();
    if (tid < 16) {
        unsafeAtomicAdd(&sums[slice * 16 + tid], sSum[tid]);
        unsafeAtomicAdd(&sqs[slice * 16 + tid], sSq[tid]);
    }
}

// fused: scale/shift from sums/sqs, h1 = elu(bn(agg1)) in LDS, y2 = dinv*(h1@W2).
// R11-verified: 32 rows/block, sW transposed (pad 68), float4 LDS reads.
__global__ void k_bn_gemm2(const unsigned* __restrict__ agg1b, const float* __restrict__ sums,
                           const float* __restrict__ sqs, const float* __restrict__ gamma,
                           const float* __restrict__ beta, const float* __restrict__ W2,
                           const float* __restrict__ dinv, bf16_t* __restrict__ y2b) {
    constexpr int RB = 32;
    __shared__ __align__(16) float sh[RB * 64];
    __shared__ __align__(16) float sWt[32 * 68];   // sWt[c*68+k] = W2[k*32+c]
    __shared__ float sscale[64], sshift[64];
    int tid = threadIdx.x;
    if (tid < 64) {
        float mu = sums[tid] * (1.0f / NN);
        float var = sqs[tid] * (1.0f / NN) - mu * mu;
        float sc = gamma[tid] * rsqrtf(var + 1e-5f);
        sscale[tid] = sc;
        sshift[tid] = beta[tid] - mu * sc;
    }
#pragma unroll
    for (int i = tid; i < 64 * 32; i += 256) {
        int k = i >> 5, c = i & 31;
        sWt[c * 68 + k] = W2[i];
    }
    __syncthreads();
    int base = blockIdx.x * RB;
#pragma unroll
    for (int rr = 0; rr < RB / 8; ++rr) {
        int r = (tid >> 5) + rr * 8, qq = tid & 31;
        int slice = qq >> 3, lane = qq & 7;
        int n = base + r;
        int col = slice * 16 + lane * 2;
        float v0 = 0.f, v1 = 0.f;
        if (n < NN) {
            unsigned u = agg1b[(size_t)slice * NN * 8 + (size_t)n * 8 + lane];
            v0 = eluf(fmaf(bflo(u), sscale[col], sshift[col]));
            v1 = eluf(fmaf(bfhi(u), sscale[col + 1], sshift[col + 1]));
        }
        sh[r * 64 + col] = v0;
        sh[r * 64 + col + 1] = v1;
    }
    __syncthreads();
    int c = tid & 31;
    bf16_t* dstp = y2b + (c >> 4) * ((NN + 1) * 16) + (c & 15);
    const float* swr = sWt + c * 68;
#pragma unroll
    for (int rr = 0; rr < RB / 8; ++rr) {
        int r = (tid >> 5) + rr * 8;
        int n = base + r;
        if (n < NN) {
            const float* shr = sh + r * 64;
            float acc = 0.f;
#pragma unroll
            for (int k4 = 0; k4 < 64; k4 += 4) {
                float4 av = *(const float4*)(shr + k4);
                float4 bv = *(const float4*)(swr + k4);
                acc = fmaf(av.x, bv.x, acc);
                acc = fmaf(av.y, bv.y, acc);
                acc = fmaf(av.z, bv.z, acc);
                acc = fmaf(av.w, bv.w, acc);
            }
            dstp[(size_t)n * 16] = f2bf(dinv[n] * acc);
        } else if (n == NN) {
            dstp[(size_t)NN * 16] = 0;            // sentinel zero row
        }
    }
}

// fused: BN stats -> scale/shift, segment pool (no atomics), 2-layer MLP head.
// agg2 read from slice-blocked layout (2 slices of 16 cols).
__global__ void k_poolmlp(const unsigned* __restrict__ agg2b, const float* __restrict__ sums,
                          const float* __restrict__ sqs, const float* __restrict__ gamma,
                          const float* __restrict__ beta, const int* __restrict__ gptr,
                          const float* __restrict__ Wm1, const float* __restrict__ bm1,
                          const float* __restrict__ Wm2, const float* __restrict__ bm2,
                          float* __restrict__ out) {
    __shared__ float sscale[32], sshift[32];
    __shared__ float red[256];
    __shared__ float gr[64];
    __shared__ float h[32];
    int tid = threadIdx.x;
    if (tid < 32) {
        float mu = sums[tid] * (1.0f / NN);
        float var = sqs[tid] * (1.0f / NN) - mu * mu;
        float sc = gamma[tid] * rsqrtf(var + 1e-5f);
        sscale[tid] = sc;
        sshift[tid] = beta[tid] - mu * sc;
    }
    __syncthreads();
    int g = blockIdx.x;
    int c = tid & 31, r = tid >> 5;
    int beg = gptr[g], end = gptr[g + 1];
    float scl = sscale[c], shf = sshift[c];
    const unsigned* ap = agg2b + (size_t)(c >> 4) * NN * 8 + ((c >> 1) & 7);
    bool hi = (c & 1);
    float s = 0.f, m = -INFINITY;
    for (int n = beg + r; n < end; n += 8) {
        unsigned u = ap[n * 8];
        float v = eluf(fmaf(hi ? bfhi(u) : bflo(u), scl, shf));
        s += v;
        m = fmaxf(m, v);
    }
    red[tid] = s;
    __syncthreads();
    int cnt = end - beg;
    if (r == 0) {
        float stot = 0.f;
#pragma unroll
        for (int i = 0; i < 8; ++i) stot += red[i * 32 + c];
        gr[c] = stot / fmaxf((float)cnt, 1.f);
    }
    __syncthreads();
    red[tid] = m;
    __syncthreads();
    if (r == 0) {
        float mtot = -INFINITY;
#pragma unroll
        for (int i = 0; i < 8; ++i) mtot = fmaxf(mtot, red[i * 32 + c]);
        gr[32 + c] = (cnt > 0) ? mtot : 0.f;
    }
    __syncthreads();
    if (tid < 32) {
        float acc = bm1[tid];
#pragma unroll
        for (int k = 0; k < 64; ++k) acc = fmaf(gr[k], Wm1[k * 32 + tid], acc);
        h[tid] = eluf(acc);
    }
    __syncthreads();
    if (tid < 2) {
        float acc = bm2[tid];
#pragma unroll
        for (int k = 0; k < 32; ++k) acc = fmaf(h[k], Wm2[k * 2 + tid], acc);
        out[g * 2 + tid] = acc;
    }
}

extern "C" void kernel_launch(void* const* d_in, const int* in_sizes, int n_in,
                              void* d_out, int out_size, void* d_ws, size_t ws_size,
                              hipStream_t stream) {
    const float* x    = (const float*)d_in[0];
    const int*   eidx = (const int*)d_in[1];
    const int*   src  = eidx;
    const int*   dst  = eidx + NE;
    const int*   batch = (const int*)d_in[3];
    const float* W1  = (const float*)d_in[4];
    const float* g1  = (const float*)d_in[6];
    const float* be1 = (const float*)d_in[7];
    const float* W2  = (const float*)d_in[8];
    const float* g2  = (const float*)d_in[10];
    const float* be2 = (const float*)d_in[11];
    const float* Wm1 = (const float*)d_in[12];
    const float* bm1 = (const float*)d_in[13];
    const float* Wm2 = (const float*)d_in[14];
    const float* bm2 = (const float*)d_in[15];
    float* out = (float*)d_out;

    // ---- workspace layout ----
    constexpr int CSRSZ = NBKT * PADREG + 16;     // fixed-stride padded csr (~10.8 MB)
    int*    bktCur  = (int*)d_ws;                 // 800 -- zeroed
    float*  S       = (float*)(bktCur + 800);     // 512 stat floats -- zeroed
    int*    degg    = (int*)(S + 512);            // 100000 -- zeroed (R14)
    int*    gptr    = degg + 100000;              // 544
    int*    csr     = gptr + 544;                 // CSRSZ (8-aligned rows)
    int2*   rowInfo = (int2*)(csr + CSRSZ);       // 100000
    float*  dinv    = (float*)(rowInfo + 100000); // 100000
    bf16_t* y1b     = (bf16_t*)(dinv + 100000);   // 4 slices x (NN+1)*16
    bf16_t* agg1b   = y1b + (NN + 1) * 64;        // 4 slices x NN*16
    bf16_t* y2b     = agg1b + NN * 64;            // 2 slices x (NN+1)*16
    bf16_t* agg2b   = y2b + (NN + 1) * 32;        // 2 slices x NN*16
    int*    ebuf    = (int*)y2b;                  // NBKT*BSTR ints (8 MB), aliases y2/agg2

    float* sum1 = S;        float* sq1 = S + 64;
    float* sum2 = S + 128;  float* sq2 = S + 160;

    // ---- init: bucket cursors + stats + degg in one memset (403 KB) ----
    (void)hipMemsetAsync(bktCur, 0, (800 + 512 + 100000) * sizeof(int), stream);

    // ---- edge bucketing (+ global degree), then FUSED {sort || gemm1} ----
    k_scatter_bkt<<<512, 1024, 0, stream>>>(src, dst, bktCur, ebuf, degg);
    k_sort_gemm1<<<NT1 + NBKT + 1, 256, 0, stream>>>(bktCur, ebuf, csr, rowInfo, dinv,
                                                     batch, gptr, x, W1, y1b, degg);

    // ---- layer 1 gather (R8 grid: 782 parts x 4 slices) ----
    k_gather<4><<<3128, 256, 0, stream>>>(rowInfo, csr, dinv,
                                          (const uint4*)y1b, (uint4*)agg1b,
                                          sum1, sq1);

    // ---- layer 2 (BN+ELU+stats fused into GEMM; y2 = dinv * h1W2, blocked) ----
    k_bn_gemm2<<<NN / 32 + 1, 256, 0, stream>>>((const unsigned*)agg1b, sum1, sq1,
                                                g1, be1, W2, dinv, y2b);
    k_gather<2><<<1564, 256, 0, stream>>>(rowInfo, csr, dinv,
                                          (const uint4*)y2b, (uint4*)agg2b,
                                          sum2, sq2);

    // ---- pooling + MLP head in one kernel ----
    k_poolmlp<<<NG, 256, 0, stream>>>((const unsigned*)agg2b, sum2, sq2, g2, be2, gptr,
                                      Wm1, bm1, Wm2, bm2, out);
}

// Round 15
// 271.219 us; speedup vs baseline: 1.1868x; 1.1868x over previous
//
#include <hip/hip_runtime.h>
#include <math.h>

constexpr int NN = 100000;
constexpr int NE = 1600000;
constexpr int NG = 512;
constexpr int NBKT = (NN + 127) / 128;   // 782 dst-buckets (128 nodes each)
constexpr int BSTR = 2560;               // fixed bucket capacity (mean 2048, sd 45 -> 11 sigma)
constexpr int PADREG = BSTR + 896;       // padded csr region per bucket
constexpr int BCAP = 3072;               // LDS staging capacity
constexpr int NT1 = (NN + 63) / 64;      // 1563 gemm1 tiles

typedef unsigned short bf16_t;
typedef unsigned int u32x4 __attribute__((ext_vector_type(4)));   // nontemporal-store-able
__device__ __forceinline__ bf16_t f2bf(float f) {
    unsigned u = __float_as_uint(f);
    unsigned r = (u + 0x7fffu + ((u >> 16) & 1u)) >> 16;   // round-nearest-even
    return (bf16_t)r;
}
__device__ __forceinline__ float bflo(unsigned u) { return __uint_as_float(u << 16); }
__device__ __forceinline__ float bfhi(unsigned u) { return __uint_as_float(u & 0xffff0000u); }
__device__ __forceinline__ unsigned bfpack(float lo, float hi) {
    return ((unsigned)f2bf(hi) << 16) | (unsigned)f2bf(lo);
}
__device__ __forceinline__ float eluf(float x) {
    return x > 0.f ? x : expm1f(x);
}

// LDS-aggregated bucket scatter (R8-verified): 512 blocks x 1024 threads.
// R14's degg global atomics REVERTED (WRITE_SIZE 25->64MB, +40us: scattered
// 4B atomics dirty full 64B lines across non-coherent XCD L2s).
__global__ __launch_bounds__(1024) void k_scatter_bkt(const int* __restrict__ src,
                                                      const int* __restrict__ dst,
                                                      int* __restrict__ bktCur,
                                                      int* __restrict__ ebuf) {
    __shared__ int cnt[NBKT];
    __shared__ int base[NBKT];
    int tid = threadIdx.x;
    for (int i = tid; i < NBKT; i += 1024) cnt[i] = 0;
    __syncthreads();
    int per = (NE + gridDim.x - 1) / gridDim.x;
    int e0 = blockIdx.x * per;
    int e1 = min(e0 + per, NE);
    for (int e = e0 + tid; e < e1; e += 1024) {
        int d = __builtin_nontemporal_load(dst + e);
        atomicAdd(&cnt[d >> 7], 1);
    }
    __syncthreads();
    for (int i = tid; i < NBKT; i += 1024) {
        int c = cnt[i];
        base[i] = i * BSTR + (c ? atomicAdd(&bktCur[i], c) : 0);
        cnt[i] = 0;                 // reuse as local cursor
    }
    __syncthreads();
    for (int e = e0 + tid; e < e1; e += 1024) {
        int s = __builtin_nontemporal_load(src + e);
        int d = __builtin_nontemporal_load(dst + e);
        int b = d >> 7;
        int off = atomicAdd(&cnt[b], 1);
        ebuf[base[b] + off] = (s << 7) | (d & 127);
    }
}

// R13 FUSED heterogeneous kernel (verified 280.9us total): blocks [0,NT1)
// run the gemm1 tile; blocks [NT1, NT1+NBKT] run bktsort (+gptr).
// gemm1's dinv dependency broken by LOCAL degree recompute (bucket scan +
// LDS histogram) -- measured ~2-5us cost, cheaper than all alternatives
// tried (R14 global atomics: +40us).
__global__ __launch_bounds__(256) void k_sort_gemm1(const int* __restrict__ bktCur,
                                                    const int* __restrict__ ebuf,
                                                    int* __restrict__ csr,
                                                    int2* __restrict__ rowInfo,
                                                    float* __restrict__ dinv,
                                                    const int* __restrict__ batch,
                                                    int* __restrict__ gptr,
                                                    const float* __restrict__ x,
                                                    const float* __restrict__ W1,
                                                    bf16_t* __restrict__ y1b) {
    __shared__ __align__(16) unsigned smem_u[8640];   // 34.6 KB union
    int tid = threadIdx.x;
    if (blockIdx.x < NT1) {
        // ---------------- gemm1 role (R5-verified core) ----------------
        float* sx = (float*)smem_u;                   // [64*68]
        float* sw = sx + 64 * 68;                     // [66*64]
        int*  deg = (int*)(sw + 66 * 64);             // [64]
        if (tid < 64) deg[tid] = 0;
        for (int i = tid; i < 66 * 32; i += 256) ((float2*)sw)[i] = ((const float2*)W1)[i];
        int base = blockIdx.x * 64;
        int rows = min(64, NN - base);
        int cnt2v = rows * 33;
        const float2* xp = (const float2*)(x + base * 66);
        for (int i = tid; i < cnt2v; i += 256) {
            int r = i / 33, kk = i - r * 33;
            ((float2*)(sx + r * 68))[kk] = xp[i];
        }
        // local degree histogram for this tile's 64 nodes (bucket slice is contiguous)
        int bkt = base >> 7;
        int half = (base >> 6) & 1;
        int ne = min(bktCur[bkt], BSTR);
        for (int i = tid; i < ne; i += 256) {
            int e = ebuf[bkt * BSTR + i];
            int d = e & 127;
            if ((d >> 6) == half) atomicAdd(&deg[d & 63], 1);
        }
        __syncthreads();
        int tr = tid >> 4, tc = tid & 15;             // 16 row-groups x 16 col-groups
        const float* sxr = sx + tr * 4 * 68;
        const float* swc = sw + tc * 4;
        float acc[4][4];
#pragma unroll
        for (int r = 0; r < 4; ++r)
#pragma unroll
            for (int c = 0; c < 4; ++c) acc[r][c] = 0.f;
#pragma unroll 4
        for (int ks = 0; ks < 64; ks += 4) {
            float4 a0 = *(const float4*)(sxr + 0 * 68 + ks);
            float4 a1 = *(const float4*)(sxr + 1 * 68 + ks);
            float4 a2 = *(const float4*)(sxr + 2 * 68 + ks);
            float4 a3 = *(const float4*)(sxr + 3 * 68 + ks);
            float4 b0 = *(const float4*)(swc + (ks + 0) * 64);
            float4 b1 = *(const float4*)(swc + (ks + 1) * 64);
            float4 b2 = *(const float4*)(swc + (ks + 2) * 64);
            float4 b3 = *(const float4*)(swc + (ks + 3) * 64);
#define FMA4(ar, bv) do { \
            acc[0][0] = fmaf(a0.ar, bv.x, acc[0][0]); acc[0][1] = fmaf(a0.ar, bv.y, acc[0][1]); \
            acc[0][2] = fmaf(a0.ar, bv.z, acc[0][2]); acc[0][3] = fmaf(a0.ar, bv.w, acc[0][3]); \
            acc[1][0] = fmaf(a1.ar, bv.x, acc[1][0]); acc[1][1] = fmaf(a1.ar, bv.y, acc[1][1]); \
            acc[1][2] = fmaf(a1.ar, bv.z, acc[1][2]); acc[1][3] = fmaf(a1.ar, bv.w, acc[1][3]); \
            acc[2][0] = fmaf(a2.ar, bv.x, acc[2][0]); acc[2][1] = fmaf(a2.ar, bv.y, acc[2][1]); \
            acc[2][2] = fmaf(a2.ar, bv.z, acc[2][2]); acc[2][3] = fmaf(a2.ar, bv.w, acc[2][3]); \
            acc[3][0] = fmaf(a3.ar, bv.x, acc[3][0]); acc[3][1] = fmaf(a3.ar, bv.y, acc[3][1]); \
            acc[3][2] = fmaf(a3.ar, bv.z, acc[3][2]); acc[3][3] = fmaf(a3.ar, bv.w, acc[3][3]); } while (0)
            FMA4(x, b0); FMA4(y, b1); FMA4(z, b2); FMA4(w, b3);
#undef FMA4
        }
        // k tail: 64, 65
#pragma unroll
        for (int k = 64; k < 66; ++k) {
            float4 bt = *(const float4*)(swc + k * 64);
#pragma unroll
            for (int r = 0; r < 4; ++r) {
                float av = sxr[r * 68 + k];
                acc[r][0] = fmaf(av, bt.x, acc[r][0]);
                acc[r][1] = fmaf(av, bt.y, acc[r][1]);
                acc[r][2] = fmaf(av, bt.z, acc[r][2]);
                acc[r][3] = fmaf(av, bt.w, acc[r][3]);
            }
        }
        // epilogue: cols tc*4..tc*4+3 all in slice tc>>2, lanes (tc&3)*4..+3
        bf16_t* dstp = y1b + (tc >> 2) * ((NN + 1) * 16) + (tc & 3) * 4;
#pragma unroll
        for (int r = 0; r < 4; ++r) {
            int nn = base + tr * 4 + r;
            if (nn < NN) {
                float di = rsqrtf((float)deg[tr * 4 + r] + 1.0f);
                ushort4 o;
                o.x = f2bf(di * acc[r][0]); o.y = f2bf(di * acc[r][1]);
                o.z = f2bf(di * acc[r][2]); o.w = f2bf(di * acc[r][3]);
                *(ushort4*)(dstp + (size_t)nn * 16) = o;
            } else if (nn == NN) {
                ushort4 o; o.x = 0; o.y = 0; o.z = 0; o.w = 0;
                *(ushort4*)(dstp + (size_t)nn * 16) = o;   // sentinel zero row
            }
        }
        return;
    }
    // ---------------- bktsort role (R8-verified) ----------------
    int b = blockIdx.x - NT1;
    if (b == NBKT) {                                  // gptr block
        for (int g = tid; g <= NG; g += 256) {
            if (g == NG) { gptr[NG] = NN; continue; }
            int lo = 0, hi = NN;
            while (lo < hi) {
                int mid = (lo + hi) >> 1;
                if (batch[mid] < g) lo = mid + 1; else hi = mid;
            }
            gptr[g] = lo;
        }
        return;
    }
    int* sbuf = (int*)smem_u;                         // [BCAP]
    int* cnt  = sbuf + BCAP;                          // [128]
    int* scn  = cnt + 128;                            // [128]
    int* cur  = scn + 128;                            // [128]
    int* padTotS = cur + 128;                         // [1]
    int base = b * BSTR;
    int n = min(bktCur[b], BSTR);
    int pbase = b * PADREG;                           // 8-aligned (PADREG % 8 == 0)
    for (int i = tid; i < n; i += 256) sbuf[i] = __builtin_nontemporal_load(ebuf + base + i);
    if (tid < 128) cnt[tid] = 0;
    __syncthreads();
    for (int i = tid; i < n; i += 256) atomicAdd(&cnt[sbuf[i] & 127], 1);
    __syncthreads();
    int deg = (tid < 128) ? cnt[tid] : 0;
    int pcnt = (deg + 7) & ~7;
    if (tid < 128) scn[tid] = pcnt;
    __syncthreads();
    for (int off = 1; off < 128; off <<= 1) {
        int t = (tid < 128 && tid >= off) ? scn[tid - off] : 0;
        __syncthreads();
        if (tid < 128) scn[tid] += t;
        __syncthreads();
    }
    if (tid == 127) *padTotS = scn[127];
    if (tid < 128) {
        int ex = scn[tid] - pcnt;
        cur[tid] = ex;
        int node = b * 128 + tid;
        if (node < NN) {
            rowInfo[node] = make_int2(pbase + ex, pbase + ex + pcnt);
            dinv[node] = rsqrtf((float)deg + 1.0f);
        }
    }
    __syncthreads();
    int padTot = *padTotS;
    for (int i = tid; i < padTot; i += 256) csr[pbase + i] = NN;   // sentinel fill
    __syncthreads();
    for (int i = tid; i < n; i += 256) {
        int p = sbuf[i];
        int pos = atomicAdd(&cur[p & 127], 1);
        csr[pbase + pos] = p >> 7;
    }
}

// Slice-blocked CSR gather (R8-verified form). 32B rows, 4 slices L2-fit;
// 2-lane groups, 16B uint4 per lane; csr cacheable + one-round-ahead
// prefetch younger than y loads.
template<int NSL>   // 4 for C=64, 2 for C=32
__global__ __launch_bounds__(256) void k_gather(const int2* __restrict__ rowInfo,
                                                const int* __restrict__ csr,
                                                const float* __restrict__ dinv,
                                                const uint4* __restrict__ yb,
                                                uint4* __restrict__ aggb,
                                                float* __restrict__ sums,
                                                float* __restrict__ sqs) {
    constexpr int SH = (NSL == 4) ? 2 : 1;
    __shared__ float sSum[16], sSq[16];
    int tid = threadIdx.x;
    if (tid < 16) { sSum[tid] = 0.f; sSq[tid] = 0.f; }
    __syncthreads();
    int slice = blockIdx.x & (NSL - 1);
    int part = blockIdx.x >> SH;
    int nparts = gridDim.x >> SH;
    int lane = tid & 1;                           // half-row selector
    int grp = tid >> 1;                           // 128 node-groups per block
    const uint4* y = yb + (size_t)slice * ((NN + 1) * 2) + lane;
    uint4* agg = aggb + (size_t)slice * (NN * 2) + lane;
    float s[8], q[8];
#pragma unroll
    for (int k = 0; k < 8; ++k) { s[k] = 0.f; q[k] = 0.f; }
    for (int n = part * 128 + grp; n < NN; n += nparts * 128) {
        int2 ri = rowInfo[n];
        float a[8];
#pragma unroll
        for (int k = 0; k < 8; ++k) a[k] = 0.f;
        int j = ri.x;
        unsigned long long c0 = 0, c1 = 0, c2 = 0, c3 = 0;
        if (j < ri.y) {                            // prime the csr pipeline
            const unsigned long long* cp = (const unsigned long long*)(csr + j);
            c0 = cp[0]; c1 = cp[1]; c2 = cp[2]; c3 = cp[3];
        }
        while (j < ri.y) {
            int i0 = (int)(c0 & 0xffffffffu), i1 = (int)(c0 >> 32);
            int i2 = (int)(c1 & 0xffffffffu), i3 = (int)(c1 >> 32);
            int i4 = (int)(c2 & 0xffffffffu), i5 = (int)(c2 >> 32);
            int i6 = (int)(c3 & 0xffffffffu), i7 = (int)(c3 >> 32);
            j += 8;
            uint4 v0 = y[i0 * 2];
            uint4 v1 = y[i1 * 2];
            uint4 v2 = y[i2 * 2];
            uint4 v3 = y[i3 * 2];
            uint4 v4 = y[i4 * 2];
            uint4 v5 = y[i5 * 2];
            uint4 v6 = y[i6 * 2];
            uint4 v7 = y[i7 * 2];
            if (j < ri.y) {                        // prefetch next round (younger than y)
                const unsigned long long* np = (const unsigned long long*)(csr + j);
                c0 = np[0]; c1 = np[1]; c2 = np[2]; c3 = np[3];
            }
#define ACC8(v) do { \
            a[0] += bflo((v).x); a[1] += bfhi((v).x); \
            a[2] += bflo((v).y); a[3] += bfhi((v).y); \
            a[4] += bflo((v).z); a[5] += bfhi((v).z); \
            a[6] += bflo((v).w); a[7] += bfhi((v).w); } while (0)
            ACC8(v0); ACC8(v1); ACC8(v2); ACC8(v3);
            ACC8(v4); ACC8(v5); ACC8(v6); ACC8(v7);
#undef ACC8
        }
        uint4 vs = y[n * 2];                      // self loop
        float di = dinv[n];
        a[0] = di * (a[0] + bflo(vs.x)); a[1] = di * (a[1] + bfhi(vs.x));
        a[2] = di * (a[2] + bflo(vs.y)); a[3] = di * (a[3] + bfhi(vs.y));
        a[4] = di * (a[4] + bflo(vs.z)); a[5] = di * (a[5] + bfhi(vs.z));
        a[6] = di * (a[6] + bflo(vs.w)); a[7] = di * (a[7] + bfhi(vs.w));
        u32x4 o;
        o.x = bfpack(a[0], a[1]); o.y = bfpack(a[2], a[3]);
        o.z = bfpack(a[4], a[5]); o.w = bfpack(a[6], a[7]);
        __builtin_nontemporal_store(o, (u32x4*)(agg + n * 2));
#pragma unroll
        for (int k = 0; k < 8; ++k) {
            float av = (k == 0) ? a[0] : (k == 1) ? a[1] : (k == 2) ? a[2] : (k == 3) ? a[3]
                     : (k == 4) ? a[4] : (k == 5) ? a[5] : (k == 6) ? a[6] : a[7];
            s[k] += av; q[k] += av * av;
        }
    }
    // wave shuffle-tree over the 32 group-pairs (keeps lane parity separate),
    // then 2 threads/wave commit to LDS (64 LDS atomics/block, was 2048).
#pragma unroll
    for (int k = 0; k < 8; ++k) {
        float sv = s[k], qv = q[k];
#pragma unroll
        for (int off = 2; off < 64; off <<= 1) {
            sv += __shfl_xor(sv, off);
            qv += __shfl_xor(qv, off);
        }
        if ((tid & 63) < 2) {
            atomicAdd(&sSum[lane * 8 + k], sv);
            atomicAdd(&sSq[lane * 8 + k], qv);
        }
    }
    __syncthreads();
    if (tid < 16) {
        unsafeAtomicAdd(&sums[slice * 16 + tid], sSum[tid]);
        unsafeAtomicAdd(&sqs[slice * 16 + tid], sSq[tid]);
    }
}

// fused: scale/shift from sums/sqs, h1 = elu(bn(agg1)) in LDS, y2 = dinv*(h1@W2).
// R11-verified: 32 rows/block, sW transposed (pad 68), float4 LDS reads.
__global__ void k_bn_gemm2(const unsigned* __restrict__ agg1b, const float* __restrict__ sums,
                           const float* __restrict__ sqs, const float* __restrict__ gamma,
                           const float* __restrict__ beta, const float* __restrict__ W2,
                           const float* __restrict__ dinv, bf16_t* __restrict__ y2b) {
    constexpr int RB = 32;
    __shared__ __align__(16) float sh[RB * 64];
    __shared__ __align__(16) float sWt[32 * 68];   // sWt[c*68+k] = W2[k*32+c]
    __shared__ float sscale[64], sshift[64];
    int tid = threadIdx.x;
    if (tid < 64) {
        float mu = sums[tid] * (1.0f / NN);
        float var = sqs[tid] * (1.0f / NN) - mu * mu;
        float sc = gamma[tid] * rsqrtf(var + 1e-5f);
        sscale[tid] = sc;
        sshift[tid] = beta[tid] - mu * sc;
    }
#pragma unroll
    for (int i = tid; i < 64 * 32; i += 256) {
        int k = i >> 5, c = i & 31;
        sWt[c * 68 + k] = W2[i];
    }
    __syncthreads();
    int base = blockIdx.x * RB;
#pragma unroll
    for (int rr = 0; rr < RB / 8; ++rr) {
        int r = (tid >> 5) + rr * 8, qq = tid & 31;
        int slice = qq >> 3, lane = qq & 7;
        int n = base + r;
        int col = slice * 16 + lane * 2;
        float v0 = 0.f, v1 = 0.f;
        if (n < NN) {
            unsigned u = agg1b[(size_t)slice * NN * 8 + (size_t)n * 8 + lane];
            v0 = eluf(fmaf(bflo(u), sscale[col], sshift[col]));
            v1 = eluf(fmaf(bfhi(u), sscale[col + 1], sshift[col + 1]));
        }
        sh[r * 64 + col] = v0;
        sh[r * 64 + col + 1] = v1;
    }
    __syncthreads();
    int c = tid & 31;
    bf16_t* dstp = y2b + (c >> 4) * ((NN + 1) * 16) + (c & 15);
    const float* swr = sWt + c * 68;
#pragma unroll
    for (int rr = 0; rr < RB / 8; ++rr) {
        int r = (tid >> 5) + rr * 8;
        int n = base + r;
        if (n < NN) {
            const float* shr = sh + r * 64;
            float acc = 0.f;
#pragma unroll
            for (int k4 = 0; k4 < 64; k4 += 4) {
                float4 av = *(const float4*)(shr + k4);
                float4 bv = *(const float4*)(swr + k4);
                acc = fmaf(av.x, bv.x, acc);
                acc = fmaf(av.y, bv.y, acc);
                acc = fmaf(av.z, bv.z, acc);
                acc = fmaf(av.w, bv.w, acc);
            }
            dstp[(size_t)n * 16] = f2bf(dinv[n] * acc);
        } else if (n == NN) {
            dstp[(size_t)NN * 16] = 0;            // sentinel zero row
        }
    }
}

// fused: BN stats -> scale/shift, segment pool (no atomics), 2-layer MLP head.
// R15: 1024 threads/block (was 256) -> 32 waves/CU occupancy cap (was 8).
// poolmlp reads 12.8MB of strided agg2 rows, latency-bound at 25% cap;
// 4x TLP hides the per-load latency. Per-column accumulation order
// preserved (r-strided partials reduced in same i-ascending order).
__global__ __launch_bounds__(1024) void k_poolmlp(const unsigned* __restrict__ agg2b,
                          const float* __restrict__ sums,
                          const float* __restrict__ sqs, const float* __restrict__ gamma,
                          const float* __restrict__ beta, const int* __restrict__ gptr,
                          const float* __restrict__ Wm1, const float* __restrict__ bm1,
                          const float* __restrict__ Wm2, const float* __restrict__ bm2,
                          float* __restrict__ out) {
    __shared__ float sscale[32], sshift[32];
    __shared__ float red[1024];
    __shared__ float gr[64];
    __shared__ float h[32];
    int tid = threadIdx.x;
    if (tid < 32) {
        float mu = sums[tid] * (1.0f / NN);
        float var = sqs[tid] * (1.0f / NN) - mu * mu;
        float sc = gamma[tid] * rsqrtf(var + 1e-5f);
        sscale[tid] = sc;
        sshift[tid] = beta[tid] - mu * sc;
    }
    __syncthreads();
    int g = blockIdx.x;
    int c = tid & 31, r = tid >> 5;               // r in [0,32)
    int beg = gptr[g], end = gptr[g + 1];
    float scl = sscale[c], shf = sshift[c];
    const unsigned* ap = agg2b + (size_t)(c >> 4) * NN * 8 + ((c >> 1) & 7);
    bool hi = (c & 1);
    float s = 0.f, m = -INFINITY;
    for (int n = beg + r; n < end; n += 32) {
        unsigned u = ap[n * 8];
        float v = eluf(fmaf(hi ? bfhi(u) : bflo(u), scl, shf));
        s += v;
        m = fmaxf(m, v);
    }
    red[tid] = s;
    __syncthreads();
    int cnt = end - beg;
    if (r == 0) {
        float stot = 0.f;
#pragma unroll
        for (int i = 0; i < 32; ++i) stot += red[i * 32 + c];
        gr[c] = stot / fmaxf((float)cnt, 1.f);
    }
    __syncthreads();
    red[tid] = m;
    __syncthreads();
    if (r == 0) {
        float mtot = -INFINITY;
#pragma unroll
        for (int i = 0; i < 32; ++i) mtot = fmaxf(mtot, red[i * 32 + c]);
        gr[32 + c] = (cnt > 0) ? mtot : 0.f;
    }
    __syncthreads();
    if (tid < 32) {
        float acc = bm1[tid];
#pragma unroll
        for (int k = 0; k < 64; ++k) acc = fmaf(gr[k], Wm1[k * 32 + tid], acc);
        h[tid] = eluf(acc);
    }
    __syncthreads();
    if (tid < 2) {
        float acc = bm2[tid];
#pragma unroll
        for (int k = 0; k < 32; ++k) acc = fmaf(h[k], Wm2[k * 2 + tid], acc);
        out[g * 2 + tid] = acc;
    }
}

extern "C" void kernel_launch(void* const* d_in, const int* in_sizes, int n_in,
                              void* d_out, int out_size, void* d_ws, size_t ws_size,
                              hipStream_t stream) {
    const float* x    = (const float*)d_in[0];
    const int*   eidx = (const int*)d_in[1];
    const int*   src  = eidx;
    const int*   dst  = eidx + NE;
    const int*   batch = (const int*)d_in[3];
    const float* W1  = (const float*)d_in[4];
    const float* g1  = (const float*)d_in[6];
    const float* be1 = (const float*)d_in[7];
    const float* W2  = (const float*)d_in[8];
    const float* g2  = (const float*)d_in[10];
    const float* be2 = (const float*)d_in[11];
    const float* Wm1 = (const float*)d_in[12];
    const float* bm1 = (const float*)d_in[13];
    const float* Wm2 = (const float*)d_in[14];
    const float* bm2 = (const float*)d_in[15];
    float* out = (float*)d_out;

    // ---- workspace layout ----
    constexpr int CSRSZ = NBKT * PADREG + 16;     // fixed-stride padded csr (~10.8 MB)
    int*    bktCur  = (int*)d_ws;                 // 800 -- zeroed
    float*  S       = (float*)(bktCur + 800);     // 512 stat floats -- zeroed
    int*    gptr    = (int*)(S + 512);            // 544
    int*    csr     = gptr + 544;                 // CSRSZ (8-aligned rows)
    int2*   rowInfo = (int2*)(csr + CSRSZ);       // 100000
    float*  dinv    = (float*)(rowInfo + 100000); // 100000
    bf16_t* y1b     = (bf16_t*)(dinv + 100000);   // 4 slices x (NN+1)*16
    bf16_t* agg1b   = y1b + (NN + 1) * 64;        // 4 slices x NN*16
    bf16_t* y2b     = agg1b + NN * 64;            // 2 slices x (NN+1)*16
    bf16_t* agg2b   = y2b + (NN + 1) * 32;        // 2 slices x NN*16
    int*    ebuf    = (int*)y2b;                  // NBKT*BSTR ints (8 MB), aliases y2/agg2

    float* sum1 = S;        float* sq1 = S + 64;
    float* sum2 = S + 128;  float* sq2 = S + 160;

    // ---- init: bucket cursors + stats in one memset ----
    (void)hipMemsetAsync(bktCur, 0, (800 + 512) * sizeof(int), stream);

    // ---- edge bucketing, then FUSED {bucket-sort || layer-1 GEMM} ----
    k_scatter_bkt<<<512, 1024, 0, stream>>>(src, dst, bktCur, ebuf);
    k_sort_gemm1<<<NT1 + NBKT + 1, 256, 0, stream>>>(bktCur, ebuf, csr, rowInfo, dinv,
                                                     batch, gptr, x, W1, y1b);

    // ---- layer 1 gather (R8 grid: 782 parts x 4 slices) ----
    k_gather<4><<<3128, 256, 0, stream>>>(rowInfo, csr, dinv,
                                          (const uint4*)y1b, (uint4*)agg1b,
                                          sum1, sq1);

    // ---- layer 2 (BN+ELU+stats fused into GEMM; y2 = dinv * h1W2, blocked) ----
    k_bn_gemm2<<<NN / 32 + 1, 256, 0, stream>>>((const unsigned*)agg1b, sum1, sq1,
                                                g1, be1, W2, dinv, y2b);
    k_gather<2><<<1564, 256, 0, stream>>>(rowInfo, csr, dinv,
                                          (const uint4*)y2b, (uint4*)agg2b,
                                          sum2, sq2);

    // ---- pooling + MLP head in one kernel (R15: 1024 threads) ----
    k_poolmlp<<<NG, 1024, 0, stream>>>((const unsigned*)agg2b, sum2, sq2, g2, be2, gptr,
                                       Wm1, bm1, Wm2, bm2, out);
}

// Round 16
// 269.786 us; speedup vs baseline: 1.1932x; 1.0053x over previous
//
#include <hip/hip_runtime.h>
#include <math.h>

constexpr int NN = 100000;
constexpr int NE = 1600000;
constexpr int NG = 512;
constexpr int NBKT = (NN + 127) / 128;   // 782 dst-buckets (128 nodes each)
constexpr int BSTR = 2560;               // fixed bucket capacity (mean 2048, sd 45 -> 11 sigma)
constexpr int PADREG = BSTR + 896;       // padded csr region per bucket
constexpr int BCAP = 3072;               // LDS staging capacity

typedef unsigned short bf16_t;
typedef unsigned int u32x4 __attribute__((ext_vector_type(4)));   // nontemporal-store-able
__device__ __forceinline__ bf16_t f2bf(float f) {
    unsigned u = __float_as_uint(f);
    unsigned r = (u + 0x7fffu + ((u >> 16) & 1u)) >> 16;   // round-nearest-even
    return (bf16_t)r;
}
__device__ __forceinline__ float bflo(unsigned u) { return __uint_as_float(u << 16); }
__device__ __forceinline__ float bfhi(unsigned u) { return __uint_as_float(u & 0xffff0000u); }
__device__ __forceinline__ unsigned bfpack(float lo, float hi) {
    return ((unsigned)f2bf(hi) << 16) | (unsigned)f2bf(lo);
}
__device__ __forceinline__ float eluf(float x) {
    return x > 0.f ? x : expm1f(x);
}

// LDS-aggregated bucket scatter (R8-verified): 512 blocks x 1024 threads.
__global__ __launch_bounds__(1024) void k_scatter_bkt(const int* __restrict__ src,
                                                      const int* __restrict__ dst,
                                                      int* __restrict__ bktCur,
                                                      int* __restrict__ ebuf) {
    __shared__ int cnt[NBKT];
    __shared__ int base[NBKT];
    int tid = threadIdx.x;
    for (int i = tid; i < NBKT; i += 1024) cnt[i] = 0;
    __syncthreads();
    int per = (NE + gridDim.x - 1) / gridDim.x;
    int e0 = blockIdx.x * per;
    int e1 = min(e0 + per, NE);
    for (int e = e0 + tid; e < e1; e += 1024) {
        int d = __builtin_nontemporal_load(dst + e);
        atomicAdd(&cnt[d >> 7], 1);
    }
    __syncthreads();
    for (int i = tid; i < NBKT; i += 1024) {
        int c = cnt[i];
        base[i] = i * BSTR + (c ? atomicAdd(&bktCur[i], c) : 0);
        cnt[i] = 0;                 // reuse as local cursor
    }
    __syncthreads();
    for (int e = e0 + tid; e < e1; e += 1024) {
        int s = __builtin_nontemporal_load(src + e);
        int d = __builtin_nontemporal_load(dst + e);
        int b = d >> 7;
        int off = atomicAdd(&cnt[b], 1);
        ebuf[base[b] + off] = (s << 7) | (d & 127);
    }
}

// FUSED heterogeneous kernel. R16: gemm1 role is now ONE BLOCK PER BUCKET
// (128 nodes, two sequential 64-row tiles reusing sx) -> bucket scanned ONCE
// (was twice: 12.8->6.4MB redundant reads, 3.2M->1.6M LDS histogram atomics,
// conflicts ~halved), W1 staging amortized 2x. Blocks [0,NBKT): gemm1 role;
// [NBKT,2*NBKT): bktsort; 2*NBKT: gptr.
__global__ __launch_bounds__(256) void k_sort_gemm1(const int* __restrict__ bktCur,
                                                    const int* __restrict__ ebuf,
                                                    int* __restrict__ csr,
                                                    int2* __restrict__ rowInfo,
                                                    float* __restrict__ dinv,
                                                    const int* __restrict__ batch,
                                                    int* __restrict__ gptr,
                                                    const float* __restrict__ x,
                                                    const float* __restrict__ W1,
                                                    bf16_t* __restrict__ y1b) {
    __shared__ __align__(16) unsigned smem_u[8704];   // 34.8 KB union
    int tid = threadIdx.x;
    if (blockIdx.x < NBKT) {
        // ---------------- gemm1 role: bucket blockIdx.x, 2 tiles ----------------
        float* sx = (float*)smem_u;                   // [64*68]
        float* sw = sx + 64 * 68;                     // [66*64]
        int*  deg = (int*)(sw + 66 * 64);             // [128]
        if (tid < 128) deg[tid] = 0;
        for (int i = tid; i < 66 * 32; i += 256) ((float2*)sw)[i] = ((const float2*)W1)[i];
        int bkt = blockIdx.x;
        int base0 = bkt * 128;
        // single bucket scan -> 128-node degree histogram
        int ne = min(bktCur[bkt], BSTR);
        for (int i = tid; i < ne; i += 256)
            atomicAdd(&deg[ebuf[bkt * BSTR + i] & 127], 1);
#pragma unroll
        for (int t = 0; t < 2; ++t) {
            int tbase = base0 + t * 64;
            if (tbase > NN) break;                    // beyond sentinel: nothing to do
            int rows = min(64, NN - tbase);           // valid x rows (may be <=0 for tail)
            if (t == 1) __syncthreads();              // sx reuse: wait for tile-A reads
            if (rows > 0) {
                int cnt2v = rows * 33;
                const float2* xp = (const float2*)(x + (size_t)tbase * 66);
                for (int i = tid; i < cnt2v; i += 256) {
                    int r = i / 33, kk = i - r * 33;
                    ((float2*)(sx + r * 68))[kk] = xp[i];
                }
            }
            __syncthreads();                          // sx + sw + deg ready
            int tr = tid >> 4, tc = tid & 15;         // 16 row-groups x 16 col-groups
            const float* sxr = sx + tr * 4 * 68;
            const float* swc = sw + tc * 4;
            float acc[4][4];
#pragma unroll
            for (int r = 0; r < 4; ++r)
#pragma unroll
                for (int c = 0; c < 4; ++c) acc[r][c] = 0.f;
#pragma unroll 4
            for (int ks = 0; ks < 64; ks += 4) {
                float4 a0 = *(const float4*)(sxr + 0 * 68 + ks);
                float4 a1 = *(const float4*)(sxr + 1 * 68 + ks);
                float4 a2 = *(const float4*)(sxr + 2 * 68 + ks);
                float4 a3 = *(const float4*)(sxr + 3 * 68 + ks);
                float4 b0 = *(const float4*)(swc + (ks + 0) * 64);
                float4 b1 = *(const float4*)(swc + (ks + 1) * 64);
                float4 b2 = *(const float4*)(swc + (ks + 2) * 64);
                float4 b3 = *(const float4*)(swc + (ks + 3) * 64);
#define FMA4(ar, bv) do { \
                acc[0][0] = fmaf(a0.ar, bv.x, acc[0][0]); acc[0][1] = fmaf(a0.ar, bv.y, acc[0][1]); \
                acc[0][2] = fmaf(a0.ar, bv.z, acc[0][2]); acc[0][3] = fmaf(a0.ar, bv.w, acc[0][3]); \
                acc[1][0] = fmaf(a1.ar, bv.x, acc[1][0]); acc[1][1] = fmaf(a1.ar, bv.y, acc[1][1]); \
                acc[1][2] = fmaf(a1.ar, bv.z, acc[1][2]); acc[1][3] = fmaf(a1.ar, bv.w, acc[1][3]); \
                acc[2][0] = fmaf(a2.ar, bv.x, acc[2][0]); acc[2][1] = fmaf(a2.ar, bv.y, acc[2][1]); \
                acc[2][2] = fmaf(a2.ar, bv.z, acc[2][2]); acc[2][3] = fmaf(a2.ar, bv.w, acc[2][3]); \
                acc[3][0] = fmaf(a3.ar, bv.x, acc[3][0]); acc[3][1] = fmaf(a3.ar, bv.y, acc[3][1]); \
                acc[3][2] = fmaf(a3.ar, bv.z, acc[3][2]); acc[3][3] = fmaf(a3.ar, bv.w, acc[3][3]); } while (0)
                FMA4(x, b0); FMA4(y, b1); FMA4(z, b2); FMA4(w, b3);
#undef FMA4
            }
            // k tail: 64, 65
#pragma unroll
            for (int k = 64; k < 66; ++k) {
                float4 bt = *(const float4*)(swc + k * 64);
#pragma unroll
                for (int r = 0; r < 4; ++r) {
                    float av = sxr[r * 68 + k];
                    acc[r][0] = fmaf(av, bt.x, acc[r][0]);
                    acc[r][1] = fmaf(av, bt.y, acc[r][1]);
                    acc[r][2] = fmaf(av, bt.z, acc[r][2]);
                    acc[r][3] = fmaf(av, bt.w, acc[r][3]);
                }
            }
            // epilogue: cols tc*4..tc*4+3 in slice tc>>2, lanes (tc&3)*4..+3
            bf16_t* dstp = y1b + (tc >> 2) * ((NN + 1) * 16) + (tc & 3) * 4;
#pragma unroll
            for (int r = 0; r < 4; ++r) {
                int nn = tbase + tr * 4 + r;
                if (nn < NN) {
                    float di = rsqrtf((float)deg[t * 64 + tr * 4 + r] + 1.0f);
                    ushort4 o;
                    o.x = f2bf(di * acc[r][0]); o.y = f2bf(di * acc[r][1]);
                    o.z = f2bf(di * acc[r][2]); o.w = f2bf(di * acc[r][3]);
                    *(ushort4*)(dstp + (size_t)nn * 16) = o;
                } else if (nn == NN) {
                    ushort4 o; o.x = 0; o.y = 0; o.z = 0; o.w = 0;
                    *(ushort4*)(dstp + (size_t)nn * 16) = o;   // sentinel zero row
                }
            }
        }
        return;
    }
    // ---------------- bktsort role (R8-verified) ----------------
    int b = blockIdx.x - NBKT;
    if (b == NBKT) {                                  // gptr block
        for (int g = tid; g <= NG; g += 256) {
            if (g == NG) { gptr[NG] = NN; continue; }
            int lo = 0, hi = NN;
            while (lo < hi) {
                int mid = (lo + hi) >> 1;
                if (batch[mid] < g) lo = mid + 1; else hi = mid;
            }
            gptr[g] = lo;
        }
        return;
    }
    int* sbuf = (int*)smem_u;                         // [BCAP]
    int* cnt  = sbuf + BCAP;                          // [128]
    int* scn  = cnt + 128;                            // [128]
    int* cur  = scn + 128;                            // [128]
    int* padTotS = cur + 128;                         // [1]
    int base = b * BSTR;
    int n = min(bktCur[b], BSTR);
    int pbase = b * PADREG;                           // 8-aligned (PADREG % 8 == 0)
    for (int i = tid; i < n; i += 256) sbuf[i] = __builtin_nontemporal_load(ebuf + base + i);
    if (tid < 128) cnt[tid] = 0;
    __syncthreads();
    for (int i = tid; i < n; i += 256) atomicAdd(&cnt[sbuf[i] & 127], 1);
    __syncthreads();
    int deg = (tid < 128) ? cnt[tid] : 0;
    int pcnt = (deg + 7) & ~7;
    if (tid < 128) scn[tid] = pcnt;
    __syncthreads();
    for (int off = 1; off < 128; off <<= 1) {
        int t = (tid < 128 && tid >= off) ? scn[tid - off] : 0;
        __syncthreads();
        if (tid < 128) scn[tid] += t;
        __syncthreads();
    }
    if (tid == 127) *padTotS = scn[127];
    if (tid < 128) {
        int ex = scn[tid] - pcnt;
        cur[tid] = ex;
        int node = b * 128 + tid;
        if (node < NN) {
            rowInfo[node] = make_int2(pbase + ex, pbase + ex + pcnt);
            dinv[node] = rsqrtf((float)deg + 1.0f);
        }
    }
    __syncthreads();
    int padTot = *padTotS;
    for (int i = tid; i < padTot; i += 256) csr[pbase + i] = NN;   // sentinel fill
    __syncthreads();
    for (int i = tid; i < n; i += 256) {
        int p = sbuf[i];
        int pos = atomicAdd(&cur[p & 127], 1);
        csr[pbase + pos] = p >> 7;
    }
}

// Slice-blocked CSR gather (R8-verified form). 32B rows, 4 slices L2-fit;
// 2-lane groups, 16B uint4 per lane; csr cacheable + one-round-ahead
// prefetch younger than y loads.
template<int NSL>   // 4 for C=64, 2 for C=32
__global__ __launch_bounds__(256) void k_gather(const int2* __restrict__ rowInfo,
                                                const int* __restrict__ csr,
                                                const float* __restrict__ dinv,
                                                const uint4* __restrict__ yb,
                                                uint4* __restrict__ aggb,
                                                float* __restrict__ sums,
                                                float* __restrict__ sqs) {
    constexpr int SH = (NSL == 4) ? 2 : 1;
    __shared__ float sSum[16], sSq[16];
    int tid = threadIdx.x;
    if (tid < 16) { sSum[tid] = 0.f; sSq[tid] = 0.f; }
    __syncthreads();
    int slice = blockIdx.x & (NSL - 1);
    int part = blockIdx.x >> SH;
    int nparts = gridDim.x >> SH;
    int lane = tid & 1;                           // half-row selector
    int grp = tid >> 1;                           // 128 node-groups per block
    const uint4* y = yb + (size_t)slice * ((NN + 1) * 2) + lane;
    uint4* agg = aggb + (size_t)slice * (NN * 2) + lane;
    float s[8], q[8];
#pragma unroll
    for (int k = 0; k < 8; ++k) { s[k] = 0.f; q[k] = 0.f; }
    for (int n = part * 128 + grp; n < NN; n += nparts * 128) {
        int2 ri = rowInfo[n];
        float a[8];
#pragma unroll
        for (int k = 0; k < 8; ++k) a[k] = 0.f;
        int j = ri.x;
        unsigned long long c0 = 0, c1 = 0, c2 = 0, c3 = 0;
        if (j < ri.y) {                            // prime the csr pipeline
            const unsigned long long* cp = (const unsigned long long*)(csr + j);
            c0 = cp[0]; c1 = cp[1]; c2 = cp[2]; c3 = cp[3];
        }
        while (j < ri.y) {
            int i0 = (int)(c0 & 0xffffffffu), i1 = (int)(c0 >> 32);
            int i2 = (int)(c1 & 0xffffffffu), i3 = (int)(c1 >> 32);
            int i4 = (int)(c2 & 0xffffffffu), i5 = (int)(c2 >> 32);
            int i6 = (int)(c3 & 0xffffffffu), i7 = (int)(c3 >> 32);
            j += 8;
            uint4 v0 = y[i0 * 2];
            uint4 v1 = y[i1 * 2];
            uint4 v2 = y[i2 * 2];
            uint4 v3 = y[i3 * 2];
            uint4 v4 = y[i4 * 2];
            uint4 v5 = y[i5 * 2];
            uint4 v6 = y[i6 * 2];
            uint4 v7 = y[i7 * 2];
            if (j < ri.y) {                        // prefetch next round (younger than y)
                const unsigned long long* np = (const unsigned long long*)(csr + j);
                c0 = np[0]; c1 = np[1]; c2 = np[2]; c3 = np[3];
            }
#define ACC8(v) do { \
            a[0] += bflo((v).x); a[1] += bfhi((v).x); \
            a[2] += bflo((v).y); a[3] += bfhi((v).y); \
            a[4] += bflo((v).z); a[5] += bfhi((v).z); \
            a[6] += bflo((v).w); a[7] += bfhi((v).w); } while (0)
            ACC8(v0); ACC8(v1); ACC8(v2); ACC8(v3);
            ACC8(v4); ACC8(v5); ACC8(v6); ACC8(v7);
#undef ACC8
        }
        uint4 vs = y[n * 2];                      // self loop
        float di = dinv[n];
        a[0] = di * (a[0] + bflo(vs.x)); a[1] = di * (a[1] + bfhi(vs.x));
        a[2] = di * (a[2] + bflo(vs.y)); a[3] = di * (a[3] + bfhi(vs.y));
        a[4] = di * (a[4] + bflo(vs.z)); a[5] = di * (a[5] + bfhi(vs.z));
        a[6] = di * (a[6] + bflo(vs.w)); a[7] = di * (a[7] + bfhi(vs.w));
        u32x4 o;
        o.x = bfpack(a[0], a[1]); o.y = bfpack(a[2], a[3]);
        o.z = bfpack(a[4], a[5]); o.w = bfpack(a[6], a[7]);
        __builtin_nontemporal_store(o, (u32x4*)(agg + n * 2));
#pragma unroll
        for (int k = 0; k < 8; ++k) {
            float av = (k == 0) ? a[0] : (k == 1) ? a[1] : (k == 2) ? a[2] : (k == 3) ? a[3]
                     : (k == 4) ? a[4] : (k == 5) ? a[5] : (k == 6) ? a[6] : a[7];
            s[k] += av; q[k] += av * av;
        }
    }
    // wave shuffle-tree over the 32 group-pairs (keeps lane parity separate),
    // then 2 threads/wave commit to LDS (64 LDS atomics/block, was 2048).
#pragma unroll
    for (int k = 0; k < 8; ++k) {
        float sv = s[k], qv = q[k];
#pragma unroll
        for (int off = 2; off < 64; off <<= 1) {
            sv += __shfl_xor(sv, off);
            qv += __shfl_xor(qv, off);
        }
        if ((tid & 63) < 2) {
            atomicAdd(&sSum[lane * 8 + k], sv);
            atomicAdd(&sSq[lane * 8 + k], qv);
        }
    }
    __syncthreads();
    if (tid < 16) {
        unsafeAtomicAdd(&sums[slice * 16 + tid], sSum[tid]);
        unsafeAtomicAdd(&sqs[slice * 16 + tid], sSq[tid]);
    }
}

// fused: scale/shift from sums/sqs, h1 = elu(bn(agg1)) in LDS, y2 = dinv*(h1@W2).
// R11-verified: 32 rows/block, sW transposed (pad 68), float4 LDS reads.
__global__ void k_bn_gemm2(const unsigned* __restrict__ agg1b, const float* __restrict__ sums,
                           const float* __restrict__ sqs, const float* __restrict__ gamma,
                           const float* __restrict__ beta, const float* __restrict__ W2,
                           const float* __restrict__ dinv, bf16_t* __restrict__ y2b) {
    constexpr int RB = 32;
    __shared__ __align__(16) float sh[RB * 64];
    __shared__ __align__(16) float sWt[32 * 68];   // sWt[c*68+k] = W2[k*32+c]
    __shared__ float sscale[64], sshift[64];
    int tid = threadIdx.x;
    if (tid < 64) {
        float mu = sums[tid] * (1.0f / NN);
        float var = sqs[tid] * (1.0f / NN) - mu * mu;
        float sc = gamma[tid] * rsqrtf(var + 1e-5f);
        sscale[tid] = sc;
        sshift[tid] = beta[tid] - mu * sc;
    }
#pragma unroll
    for (int i = tid; i < 64 * 32; i += 256) {
        int k = i >> 5, c = i & 31;
        sWt[c * 68 + k] = W2[i];
    }
    __syncthreads();
    int base = blockIdx.x * RB;
#pragma unroll
    for (int rr = 0; rr < RB / 8; ++rr) {
        int r = (tid >> 5) + rr * 8, qq = tid & 31;
        int slice = qq >> 3, lane = qq & 7;
        int n = base + r;
        int col = slice * 16 + lane * 2;
        float v0 = 0.f, v1 = 0.f;
        if (n < NN) {
            unsigned u = agg1b[(size_t)slice * NN * 8 + (size_t)n * 8 + lane];
            v0 = eluf(fmaf(bflo(u), sscale[col], sshift[col]));
            v1 = eluf(fmaf(bfhi(u), sscale[col + 1], sshift[col + 1]));
        }
        sh[r * 64 + col] = v0;
        sh[r * 64 + col + 1] = v1;
    }
    __syncthreads();
    int c = tid & 31;
    bf16_t* dstp = y2b + (c >> 4) * ((NN + 1) * 16) + (c & 15);
    const float* swr = sWt + c * 68;
#pragma unroll
    for (int rr = 0; rr < RB / 8; ++rr) {
        int r = (tid >> 5) + rr * 8;
        int n = base + r;
        if (n < NN) {
            const float* shr = sh + r * 64;
            float acc = 0.f;
#pragma unroll
            for (int k4 = 0; k4 < 64; k4 += 4) {
                float4 av = *(const float4*)(shr + k4);
                float4 bv = *(const float4*)(swr + k4);
                acc = fmaf(av.x, bv.x, acc);
                acc = fmaf(av.y, bv.y, acc);
                acc = fmaf(av.z, bv.z, acc);
                acc = fmaf(av.w, bv.w, acc);
            }
            dstp[(size_t)n * 16] = f2bf(dinv[n] * acc);
        } else if (n == NN) {
            dstp[(size_t)NN * 16] = 0;            // sentinel zero row
        }
    }
}

// fused: BN stats -> scale/shift, segment pool (no atomics), 2-layer MLP head.
// R15-verified: 1024 threads/block -> 32 waves/CU occupancy cap.
__global__ __launch_bounds__(1024) void k_poolmlp(const unsigned* __restrict__ agg2b,
                          const float* __restrict__ sums,
                          const float* __restrict__ sqs, const float* __restrict__ gamma,
                          const float* __restrict__ beta, const int* __restrict__ gptr,
                          const float* __restrict__ Wm1, const float* __restrict__ bm1,
                          const float* __restrict__ Wm2, const float* __restrict__ bm2,
                          float* __restrict__ out) {
    __shared__ float sscale[32], sshift[32];
    __shared__ float red[1024];
    __shared__ float gr[64];
    __shared__ float h[32];
    int tid = threadIdx.x;
    if (tid < 32) {
        float mu = sums[tid] * (1.0f / NN);
        float var = sqs[tid] * (1.0f / NN) - mu * mu;
        float sc = gamma[tid] * rsqrtf(var + 1e-5f);
        sscale[tid] = sc;
        sshift[tid] = beta[tid] - mu * sc;
    }
    __syncthreads();
    int g = blockIdx.x;
    int c = tid & 31, r = tid >> 5;               // r in [0,32)
    int beg = gptr[g], end = gptr[g + 1];
    float scl = sscale[c], shf = sshift[c];
    const unsigned* ap = agg2b + (size_t)(c >> 4) * NN * 8 + ((c >> 1) & 7);
    bool hi = (c & 1);
    float s = 0.f, m = -INFINITY;
    for (int n = beg + r; n < end; n += 32) {
        unsigned u = ap[n * 8];
        float v = eluf(fmaf(hi ? bfhi(u) : bflo(u), scl, shf));
        s += v;
        m = fmaxf(m, v);
    }
    red[tid] = s;
    __syncthreads();
    int cnt = end - beg;
    if (r == 0) {
        float stot = 0.f;
#pragma unroll
        for (int i = 0; i < 32; ++i) stot += red[i * 32 + c];
        gr[c] = stot / fmaxf((float)cnt, 1.f);
    }
    __syncthreads();
    red[tid] = m;
    __syncthreads();
    if (r == 0) {
        float mtot = -INFINITY;
#pragma unroll
        for (int i = 0; i < 32; ++i) mtot = fmaxf(mtot, red[i * 32 + c]);
        gr[32 + c] = (cnt > 0) ? mtot : 0.f;
    }
    __syncthreads();
    if (tid < 32) {
        float acc = bm1[tid];
#pragma unroll
        for (int k = 0; k < 64; ++k) acc = fmaf(gr[k], Wm1[k * 32 + tid], acc);
        h[tid] = eluf(acc);
    }
    __syncthreads();
    if (tid < 2) {
        float acc = bm2[tid];
#pragma unroll
        for (int k = 0; k < 32; ++k) acc = fmaf(h[k], Wm2[k * 2 + tid], acc);
        out[g * 2 + tid] = acc;
    }
}

extern "C" void kernel_launch(void* const* d_in, const int* in_sizes, int n_in,
                              void* d_out, int out_size, void* d_ws, size_t ws_size,
                              hipStream_t stream) {
    const float* x    = (const float*)d_in[0];
    const int*   eidx = (const int*)d_in[1];
    const int*   src  = eidx;
    const int*   dst  = eidx + NE;
    const int*   batch = (const int*)d_in[3];
    const float* W1  = (const float*)d_in[4];
    const float* g1  = (const float*)d_in[6];
    const float* be1 = (const float*)d_in[7];
    const float* W2  = (const float*)d_in[8];
    const float* g2  = (const float*)d_in[10];
    const float* be2 = (const float*)d_in[11];
    const float* Wm1 = (const float*)d_in[12];
    const float* bm1 = (const float*)d_in[13];
    const float* Wm2 = (const float*)d_in[14];
    const float* bm2 = (const float*)d_in[15];
    float* out = (float*)d_out;

    // ---- workspace layout ----
    constexpr int CSRSZ = NBKT * PADREG + 16;     // fixed-stride padded csr (~10.8 MB)
    int*    bktCur  = (int*)d_ws;                 // 800 -- zeroed
    float*  S       = (float*)(bktCur + 800);     // 512 stat floats -- zeroed
    int*    gptr    = (int*)(S + 512);            // 544
    int*    csr     = gptr + 544;                 // CSRSZ (8-aligned rows)
    int2*   rowInfo = (int2*)(csr + CSRSZ);       // 100000
    float*  dinv    = (float*)(rowInfo + 100000); // 100000
    bf16_t* y1b     = (bf16_t*)(dinv + 100000);   // 4 slices x (NN+1)*16
    bf16_t* agg1b   = y1b + (NN + 1) * 64;        // 4 slices x NN*16
    bf16_t* y2b     = agg1b + NN * 64;            // 2 slices x (NN+1)*16
    bf16_t* agg2b   = y2b + (NN + 1) * 32;        // 2 slices x NN*16
    int*    ebuf    = (int*)y2b;                  // NBKT*BSTR ints (8 MB), aliases y2/agg2

    float* sum1 = S;        float* sq1 = S + 64;
    float* sum2 = S + 128;  float* sq2 = S + 160;

    // ---- init: bucket cursors + stats in one memset ----
    (void)hipMemsetAsync(bktCur, 0, (800 + 512) * sizeof(int), stream);

    // ---- edge bucketing, then FUSED {bucket-sort || layer-1 GEMM} ----
    k_scatter_bkt<<<512, 1024, 0, stream>>>(src, dst, bktCur, ebuf);
    k_sort_gemm1<<<2 * NBKT + 1, 256, 0, stream>>>(bktCur, ebuf, csr, rowInfo, dinv,
                                                   batch, gptr, x, W1, y1b);

    // ---- layer 1 gather (R8 grid: 782 parts x 4 slices) ----
    k_gather<4><<<3128, 256, 0, stream>>>(rowInfo, csr, dinv,
                                          (const uint4*)y1b, (uint4*)agg1b,
                                          sum1, sq1);

    // ---- layer 2 (BN+ELU+stats fused into GEMM; y2 = dinv * h1W2, blocked) ----
    k_bn_gemm2<<<NN / 32 + 1, 256, 0, stream>>>((const unsigned*)agg1b, sum1, sq1,
                                                g1, be1, W2, dinv, y2b);
    k_gather<2><<<1564, 256, 0, stream>>>(rowInfo, csr, dinv,
                                          (const uint4*)y2b, (uint4*)agg2b,
                                          sum2, sq2);

    // ---- pooling + MLP head in one kernel (1024 threads) ----
    k_poolmlp<<<NG, 1024, 0, stream>>>((const unsigned*)agg2b, sum2, sq2, g2, be2, gptr,
                                       Wm1, bm1, Wm2, bm2, out);
}

// Round 17
// 255.725 us; speedup vs baseline: 1.2588x; 1.0550x over previous
//
#include <hip/hip_runtime.h>
#include <math.h>

constexpr int NN = 100000;
constexpr int NE = 1600000;
constexpr int NG = 512;
constexpr int NBKT = (NN + 127) / 128;   // 782 dst-buckets (128 nodes each)
constexpr int BSTR = 2560;               // fixed bucket capacity (mean 2048, sd 45 -> 11 sigma)
constexpr int PADREG = BSTR + 896;       // padded csr region per bucket
constexpr int BCAP = 3072;               // LDS staging capacity

typedef unsigned short bf16_t;
typedef unsigned int u32x4 __attribute__((ext_vector_type(4)));   // nontemporal-store-able
typedef int i32x4 __attribute__((ext_vector_type(4)));            // nontemporal-load-able
__device__ __forceinline__ bf16_t f2bf(float f) {
    unsigned u = __float_as_uint(f);
    unsigned r = (u + 0x7fffu + ((u >> 16) & 1u)) >> 16;   // round-nearest-even
    return (bf16_t)r;
}
__device__ __forceinline__ float bflo(unsigned u) { return __uint_as_float(u << 16); }
__device__ __forceinline__ float bfhi(unsigned u) { return __uint_as_float(u & 0xffff0000u); }
__device__ __forceinline__ unsigned bfpack(float lo, float hi) {
    return ((unsigned)f2bf(hi) << 16) | (unsigned)f2bf(lo);
}
__device__ __forceinline__ float eluf(float x) {
    return x > 0.f ? x : expm1f(x);
}

// LDS-aggregated bucket scatter. R17: 391 blocks x 1024 threads, 4 edges per
// thread via ONE int4 load of src and dst each, held in REGISTERS across both
// passes -> pass 2 has zero global loads (was: dst read twice + src once,
// 19.2MB scalar). 4096 edges/block keeps per-bucket write run-length ~5.
// NE and block offsets are multiples of 4 -> active threads always have a
// full aligned quad (no scalar tail).
__global__ __launch_bounds__(1024) void k_scatter_bkt(const int* __restrict__ src,
                                                      const int* __restrict__ dst,
                                                      int* __restrict__ bktCur,
                                                      int* __restrict__ ebuf) {
    __shared__ int cnt[NBKT];
    __shared__ int base[NBKT];
    int tid = threadIdx.x;
    for (int i = tid; i < NBKT; i += 1024) cnt[i] = 0;
    __syncthreads();
    int e0 = blockIdx.x * 4096;
    int e1 = min(e0 + 4096, NE);
    int e = e0 + tid * 4;
    bool act = (e + 4 <= e1);
    i32x4 sv, dv;
    sv.x = 0; sv.y = 0; sv.z = 0; sv.w = 0;
    dv = sv;
    if (act) {
        sv = __builtin_nontemporal_load((const i32x4*)(src + e));
        dv = __builtin_nontemporal_load((const i32x4*)(dst + e));
        atomicAdd(&cnt[dv.x >> 7], 1);
        atomicAdd(&cnt[dv.y >> 7], 1);
        atomicAdd(&cnt[dv.z >> 7], 1);
        atomicAdd(&cnt[dv.w >> 7], 1);
    }
    __syncthreads();
    for (int i = tid; i < NBKT; i += 1024) {
        int c = cnt[i];
        base[i] = i * BSTR + (c ? atomicAdd(&bktCur[i], c) : 0);
        cnt[i] = 0;                 // reuse as local cursor
    }
    __syncthreads();
    if (act) {
        int b, off;
        b = dv.x >> 7; off = atomicAdd(&cnt[b], 1); ebuf[base[b] + off] = (sv.x << 7) | (dv.x & 127);
        b = dv.y >> 7; off = atomicAdd(&cnt[b], 1); ebuf[base[b] + off] = (sv.y << 7) | (dv.y & 127);
        b = dv.z >> 7; off = atomicAdd(&cnt[b], 1); ebuf[base[b] + off] = (sv.z << 7) | (dv.z & 127);
        b = dv.w >> 7; off = atomicAdd(&cnt[b], 1); ebuf[base[b] + off] = (sv.w << 7) | (dv.w & 127);
    }
}

// FUSED heterogeneous kernel (R16-verified): blocks [0,NBKT): gemm1 role
// (one block per bucket, 2 tiles, single bucket scan for degrees);
// [NBKT,2*NBKT): bktsort; 2*NBKT: gptr.
__global__ __launch_bounds__(256) void k_sort_gemm1(const int* __restrict__ bktCur,
                                                    const int* __restrict__ ebuf,
                                                    int* __restrict__ csr,
                                                    int2* __restrict__ rowInfo,
                                                    float* __restrict__ dinv,
                                                    const int* __restrict__ batch,
                                                    int* __restrict__ gptr,
                                                    const float* __restrict__ x,
                                                    const float* __restrict__ W1,
                                                    bf16_t* __restrict__ y1b) {
    __shared__ __align__(16) unsigned smem_u[8704];   // 34.8 KB union
    int tid = threadIdx.x;
    if (blockIdx.x < NBKT) {
        // ---------------- gemm1 role: bucket blockIdx.x, 2 tiles ----------------
        float* sx = (float*)smem_u;                   // [64*68]
        float* sw = sx + 64 * 68;                     // [66*64]
        int*  deg = (int*)(sw + 66 * 64);             // [128]
        if (tid < 128) deg[tid] = 0;
        for (int i = tid; i < 66 * 32; i += 256) ((float2*)sw)[i] = ((const float2*)W1)[i];
        int bkt = blockIdx.x;
        int base0 = bkt * 128;
        // single bucket scan -> 128-node degree histogram
        int ne = min(bktCur[bkt], BSTR);
        for (int i = tid; i < ne; i += 256)
            atomicAdd(&deg[ebuf[bkt * BSTR + i] & 127], 1);
#pragma unroll
        for (int t = 0; t < 2; ++t) {
            int tbase = base0 + t * 64;
            if (tbase > NN) break;                    // beyond sentinel: nothing to do
            int rows = min(64, NN - tbase);           // valid x rows
            if (t == 1) __syncthreads();              // sx reuse: wait for tile-A reads
            if (rows > 0) {
                int cnt2v = rows * 33;
                const float2* xp = (const float2*)(x + (size_t)tbase * 66);
                for (int i = tid; i < cnt2v; i += 256) {
                    int r = i / 33, kk = i - r * 33;
                    ((float2*)(sx + r * 68))[kk] = xp[i];
                }
            }
            __syncthreads();                          // sx + sw + deg ready
            int tr = tid >> 4, tc = tid & 15;         // 16 row-groups x 16 col-groups
            const float* sxr = sx + tr * 4 * 68;
            const float* swc = sw + tc * 4;
            float acc[4][4];
#pragma unroll
            for (int r = 0; r < 4; ++r)
#pragma unroll
                for (int c = 0; c < 4; ++c) acc[r][c] = 0.f;
#pragma unroll 4
            for (int ks = 0; ks < 64; ks += 4) {
                float4 a0 = *(const float4*)(sxr + 0 * 68 + ks);
                float4 a1 = *(const float4*)(sxr + 1 * 68 + ks);
                float4 a2 = *(const float4*)(sxr + 2 * 68 + ks);
                float4 a3 = *(const float4*)(sxr + 3 * 68 + ks);
                float4 b0 = *(const float4*)(swc + (ks + 0) * 64);
                float4 b1 = *(const float4*)(swc + (ks + 1) * 64);
                float4 b2 = *(const float4*)(swc + (ks + 2) * 64);
                float4 b3 = *(const float4*)(swc + (ks + 3) * 64);
#define FMA4(ar, bv) do { \
                acc[0][0] = fmaf(a0.ar, bv.x, acc[0][0]); acc[0][1] = fmaf(a0.ar, bv.y, acc[0][1]); \
                acc[0][2] = fmaf(a0.ar, bv.z, acc[0][2]); acc[0][3] = fmaf(a0.ar, bv.w, acc[0][3]); \
                acc[1][0] = fmaf(a1.ar, bv.x, acc[1][0]); acc[1][1] = fmaf(a1.ar, bv.y, acc[1][1]); \
                acc[1][2] = fmaf(a1.ar, bv.z, acc[1][2]); acc[1][3] = fmaf(a1.ar, bv.w, acc[1][3]); \
                acc[2][0] = fmaf(a2.ar, bv.x, acc[2][0]); acc[2][1] = fmaf(a2.ar, bv.y, acc[2][1]); \
                acc[2][2] = fmaf(a2.ar, bv.z, acc[2][2]); acc[2][3] = fmaf(a2.ar, bv.w, acc[2][3]); \
                acc[3][0] = fmaf(a3.ar, bv.x, acc[3][0]); acc[3][1] = fmaf(a3.ar, bv.y, acc[3][1]); \
                acc[3][2] = fmaf(a3.ar, bv.z, acc[3][2]); acc[3][3] = fmaf(a3.ar, bv.w, acc[3][3]); } while (0)
                FMA4(x, b0); FMA4(y, b1); FMA4(z, b2); FMA4(w, b3);
#undef FMA4
            }
            // k tail: 64, 65
#pragma unroll
            for (int k = 64; k < 66; ++k) {
                float4 bt = *(const float4*)(swc + k * 64);
#pragma unroll
                for (int r = 0; r < 4; ++r) {
                    float av = sxr[r * 68 + k];
                    acc[r][0] = fmaf(av, bt.x, acc[r][0]);
                    acc[r][1] = fmaf(av, bt.y, acc[r][1]);
                    acc[r][2] = fmaf(av, bt.z, acc[r][2]);
                    acc[r][3] = fmaf(av, bt.w, acc[r][3]);
                }
            }
            // epilogue: cols tc*4..tc*4+3 in slice tc>>2, lanes (tc&3)*4..+3
            bf16_t* dstp = y1b + (tc >> 2) * ((NN + 1) * 16) + (tc & 3) * 4;
#pragma unroll
            for (int r = 0; r < 4; ++r) {
                int nn = tbase + tr * 4 + r;
                if (nn < NN) {
                    float di = rsqrtf((float)deg[t * 64 + tr * 4 + r] + 1.0f);
                    ushort4 o;
                    o.x = f2bf(di * acc[r][0]); o.y = f2bf(di * acc[r][1]);
                    o.z = f2bf(di * acc[r][2]); o.w = f2bf(di * acc[r][3]);
                    *(ushort4*)(dstp + (size_t)nn * 16) = o;
                } else if (nn == NN) {
                    ushort4 o; o.x = 0; o.y = 0; o.z = 0; o.w = 0;
                    *(ushort4*)(dstp + (size_t)nn * 16) = o;   // sentinel zero row
                }
            }
        }
        return;
    }
    // ---------------- bktsort role (R8-verified) ----------------
    int b = blockIdx.x - NBKT;
    if (b == NBKT) {                                  // gptr block
        for (int g = tid; g <= NG; g += 256) {
            if (g == NG) { gptr[NG] = NN; continue; }
            int lo = 0, hi = NN;
            while (lo < hi) {
                int mid = (lo + hi) >> 1;
                if (batch[mid] < g) lo = mid + 1; else hi = mid;
            }
            gptr[g] = lo;
        }
        return;
    }
    int* sbuf = (int*)smem_u;                         // [BCAP]
    int* cnt  = sbuf + BCAP;                          // [128]
    int* scn  = cnt + 128;                            // [128]
    int* cur  = scn + 128;                            // [128]
    int* padTotS = cur + 128;                         // [1]
    int base = b * BSTR;
    int n = min(bktCur[b], BSTR);
    int pbase = b * PADREG;                           // 8-aligned (PADREG % 8 == 0)
    for (int i = tid; i < n; i += 256) sbuf[i] = __builtin_nontemporal_load(ebuf + base + i);
    if (tid < 128) cnt[tid] = 0;
    __syncthreads();
    for (int i = tid; i < n; i += 256) atomicAdd(&cnt[sbuf[i] & 127], 1);
    __syncthreads();
    int deg = (tid < 128) ? cnt[tid] : 0;
    int pcnt = (deg + 7) & ~7;
    if (tid < 128) scn[tid] = pcnt;
    __syncthreads();
    for (int off = 1; off < 128; off <<= 1) {
        int t = (tid < 128 && tid >= off) ? scn[tid - off] : 0;
        __syncthreads();
        if (tid < 128) scn[tid] += t;
        __syncthreads();
    }
    if (tid == 127) *padTotS = scn[127];
    if (tid < 128) {
        int ex = scn[tid] - pcnt;
        cur[tid] = ex;
        int node = b * 128 + tid;
        if (node < NN) {
            rowInfo[node] = make_int2(pbase + ex, pbase + ex + pcnt);
            dinv[node] = rsqrtf((float)deg + 1.0f);
        }
    }
    __syncthreads();
    int padTot = *padTotS;
    for (int i = tid; i < padTot; i += 256) csr[pbase + i] = NN;   // sentinel fill
    __syncthreads();
    for (int i = tid; i < n; i += 256) {
        int p = sbuf[i];
        int pos = atomicAdd(&cur[p & 127], 1);
        csr[pbase + pos] = p >> 7;
    }
}

// Slice-blocked CSR gather (R8-verified form). 32B rows, 4 slices L2-fit;
// 2-lane groups, 16B uint4 per lane; csr cacheable + one-round-ahead
// prefetch younger than y loads.
template<int NSL>   // 4 for C=64, 2 for C=32
__global__ __launch_bounds__(256) void k_gather(const int2* __restrict__ rowInfo,
                                                const int* __restrict__ csr,
                                                const float* __restrict__ dinv,
                                                const uint4* __restrict__ yb,
                                                uint4* __restrict__ aggb,
                                                float* __restrict__ sums,
                                                float* __restrict__ sqs) {
    constexpr int SH = (NSL == 4) ? 2 : 1;
    __shared__ float sSum[16], sSq[16];
    int tid = threadIdx.x;
    if (tid < 16) { sSum[tid] = 0.f; sSq[tid] = 0.f; }
    __syncthreads();
    int slice = blockIdx.x & (NSL - 1);
    int part = blockIdx.x >> SH;
    int nparts = gridDim.x >> SH;
    int lane = tid & 1;                           // half-row selector
    int grp = tid >> 1;                           // 128 node-groups per block
    const uint4* y = yb + (size_t)slice * ((NN + 1) * 2) + lane;
    uint4* agg = aggb + (size_t)slice * (NN * 2) + lane;
    float s[8], q[8];
#pragma unroll
    for (int k = 0; k < 8; ++k) { s[k] = 0.f; q[k] = 0.f; }
    for (int n = part * 128 + grp; n < NN; n += nparts * 128) {
        int2 ri = rowInfo[n];
        float a[8];
#pragma unroll
        for (int k = 0; k < 8; ++k) a[k] = 0.f;
        int j = ri.x;
        unsigned long long c0 = 0, c1 = 0, c2 = 0, c3 = 0;
        if (j < ri.y) {                            // prime the csr pipeline
            const unsigned long long* cp = (const unsigned long long*)(csr + j);
            c0 = cp[0]; c1 = cp[1]; c2 = cp[2]; c3 = cp[3];
        }
        while (j < ri.y) {
            int i0 = (int)(c0 & 0xffffffffu), i1 = (int)(c0 >> 32);
            int i2 = (int)(c1 & 0xffffffffu), i3 = (int)(c1 >> 32);
            int i4 = (int)(c2 & 0xffffffffu), i5 = (int)(c2 >> 32);
            int i6 = (int)(c3 & 0xffffffffu), i7 = (int)(c3 >> 32);
            j += 8;
            uint4 v0 = y[i0 * 2];
            uint4 v1 = y[i1 * 2];
            uint4 v2 = y[i2 * 2];
            uint4 v3 = y[i3 * 2];
            uint4 v4 = y[i4 * 2];
            uint4 v5 = y[i5 * 2];
            uint4 v6 = y[i6 * 2];
            uint4 v7 = y[i7 * 2];
            if (j < ri.y) {                        // prefetch next round (younger than y)
                const unsigned long long* np = (const unsigned long long*)(csr + j);
                c0 = np[0]; c1 = np[1]; c2 = np[2]; c3 = np[3];
            }
#define ACC8(v) do { \
            a[0] += bflo((v).x); a[1] += bfhi((v).x); \
            a[2] += bflo((v).y); a[3] += bfhi((v).y); \
            a[4] += bflo((v).z); a[5] += bfhi((v).z); \
            a[6] += bflo((v).w); a[7] += bfhi((v).w); } while (0)
            ACC8(v0); ACC8(v1); ACC8(v2); ACC8(v3);
            ACC8(v4); ACC8(v5); ACC8(v6); ACC8(v7);
#undef ACC8
        }
        uint4 vs = y[n * 2];                      // self loop
        float di = dinv[n];
        a[0] = di * (a[0] + bflo(vs.x)); a[1] = di * (a[1] + bfhi(vs.x));
        a[2] = di * (a[2] + bflo(vs.y)); a[3] = di * (a[3] + bfhi(vs.y));
        a[4] = di * (a[4] + bflo(vs.z)); a[5] = di * (a[5] + bfhi(vs.z));
        a[6] = di * (a[6] + bflo(vs.w)); a[7] = di * (a[7] + bfhi(vs.w));
        u32x4 o;
        o.x = bfpack(a[0], a[1]); o.y = bfpack(a[2], a[3]);
        o.z = bfpack(a[4], a[5]); o.w = bfpack(a[6], a[7]);
        __builtin_nontemporal_store(o, (u32x4*)(agg + n * 2));
#pragma unroll
        for (int k = 0; k < 8; ++k) {
            float av = (k == 0) ? a[0] : (k == 1) ? a[1] : (k == 2) ? a[2] : (k == 3) ? a[3]
                     : (k == 4) ? a[4] : (k == 5) ? a[5] : (k == 6) ? a[6] : a[7];
            s[k] += av; q[k] += av * av;
        }
    }
    // wave shuffle-tree over the 32 group-pairs (keeps lane parity separate),
    // then 2 threads/wave commit to LDS (64 LDS atomics/block, was 2048).
#pragma unroll
    for (int k = 0; k < 8; ++k) {
        float sv = s[k], qv = q[k];
#pragma unroll
        for (int off = 2; off < 64; off <<= 1) {
            sv += __shfl_xor(sv, off);
            qv += __shfl_xor(qv, off);
        }
        if ((tid & 63) < 2) {
            atomicAdd(&sSum[lane * 8 + k], sv);
            atomicAdd(&sSq[lane * 8 + k], qv);
        }
    }
    __syncthreads();
    if (tid < 16) {
        unsafeAtomicAdd(&sums[slice * 16 + tid], sSum[tid]);
        unsafeAtomicAdd(&sqs[slice * 16 + tid], sSq[tid]);
    }
}

// fused: scale/shift from sums/sqs, h1 = elu(bn(agg1)) in LDS, y2 = dinv*(h1@W2).
// R11-verified: 32 rows/block, sW transposed (pad 68), float4 LDS reads.
__global__ void k_bn_gemm2(const unsigned* __restrict__ agg1b, const float* __restrict__ sums,
                           const float* __restrict__ sqs, const float* __restrict__ gamma,
                           const float* __restrict__ beta, const float* __restrict__ W2,
                           const float* __restrict__ dinv, bf16_t* __restrict__ y2b) {
    constexpr int RB = 32;
    __shared__ __align__(16) float sh[RB * 64];
    __shared__ __align__(16) float sWt[32 * 68];   // sWt[c*68+k] = W2[k*32+c]
    __shared__ float sscale[64], sshift[64];
    int tid = threadIdx.x;
    if (tid < 64) {
        float mu = sums[tid] * (1.0f / NN);
        float var = sqs[tid] * (1.0f / NN) - mu * mu;
        float sc = gamma[tid] * rsqrtf(var + 1e-5f);
        sscale[tid] = sc;
        sshift[tid] = beta[tid] - mu * sc;
    }
#pragma unroll
    for (int i = tid; i < 64 * 32; i += 256) {
        int k = i >> 5, c = i & 31;
        sWt[c * 68 + k] = W2[i];
    }
    __syncthreads();
    int base = blockIdx.x * RB;
#pragma unroll
    for (int rr = 0; rr < RB / 8; ++rr) {
        int r = (tid >> 5) + rr * 8, qq = tid & 31;
        int slice = qq >> 3, lane = qq & 7;
        int n = base + r;
        int col = slice * 16 + lane * 2;
        float v0 = 0.f, v1 = 0.f;
        if (n < NN) {
            unsigned u = agg1b[(size_t)slice * NN * 8 + (size_t)n * 8 + lane];
            v0 = eluf(fmaf(bflo(u), sscale[col], sshift[col]));
            v1 = eluf(fmaf(bfhi(u), sscale[col + 1], sshift[col + 1]));
        }
        sh[r * 64 + col] = v0;
        sh[r * 64 + col + 1] = v1;
    }
    __syncthreads();
    int c = tid & 31;
    bf16_t* dstp = y2b + (c >> 4) * ((NN + 1) * 16) + (c & 15);
    const float* swr = sWt + c * 68;
#pragma unroll
    for (int rr = 0; rr < RB / 8; ++rr) {
        int r = (tid >> 5) + rr * 8;
        int n = base + r;
        if (n < NN) {
            const float* shr = sh + r * 64;
            float acc = 0.f;
#pragma unroll
            for (int k4 = 0; k4 < 64; k4 += 4) {
                float4 av = *(const float4*)(shr + k4);
                float4 bv = *(const float4*)(swr + k4);
                acc = fmaf(av.x, bv.x, acc);
                acc = fmaf(av.y, bv.y, acc);
                acc = fmaf(av.z, bv.z, acc);
                acc = fmaf(av.w, bv.w, acc);
            }
            dstp[(size_t)n * 16] = f2bf(dinv[n] * acc);
        } else if (n == NN) {
            dstp[(size_t)NN * 16] = 0;            // sentinel zero row
        }
    }
}

// fused: BN stats -> scale/shift, segment pool (no atomics), 2-layer MLP head.
// R15-verified: 1024 threads/block -> 32 waves/CU occupancy cap.
__global__ __launch_bounds__(1024) void k_poolmlp(const unsigned* __restrict__ agg2b,
                          const float* __restrict__ sums,
                          const float* __restrict__ sqs, const float* __restrict__ gamma,
                          const float* __restrict__ beta, const int* __restrict__ gptr,
                          const float* __restrict__ Wm1, const float* __restrict__ bm1,
                          const float* __restrict__ Wm2, const float* __restrict__ bm2,
                          float* __restrict__ out) {
    __shared__ float sscale[32], sshift[32];
    __shared__ float red[1024];
    __shared__ float gr[64];
    __shared__ float h[32];
    int tid = threadIdx.x;
    if (tid < 32) {
        float mu = sums[tid] * (1.0f / NN);
        float var = sqs[tid] * (1.0f / NN) - mu * mu;
        float sc = gamma[tid] * rsqrtf(var + 1e-5f);
        sscale[tid] = sc;
        sshift[tid] = beta[tid] - mu * sc;
    }
    __syncthreads();
    int g = blockIdx.x;
    int c = tid & 31, r = tid >> 5;               // r in [0,32)
    int beg = gptr[g], end = gptr[g + 1];
    float scl = sscale[c], shf = sshift[c];
    const unsigned* ap = agg2b + (size_t)(c >> 4) * NN * 8 + ((c >> 1) & 7);
    bool hi = (c & 1);
    float s = 0.f, m = -INFINITY;
    for (int n = beg + r; n < end; n += 32) {
        unsigned u = ap[n * 8];
        float v = eluf(fmaf(hi ? bfhi(u) : bflo(u), scl, shf));
        s += v;
        m = fmaxf(m, v);
    }
    red[tid] = s;
    __syncthreads();
    int cnt = end - beg;
    if (r == 0) {
        float stot = 0.f;
#pragma unroll
        for (int i = 0; i < 32; ++i) stot += red[i * 32 + c];
        gr[c] = stot / fmaxf((float)cnt, 1.f);
    }
    __syncthreads();
    red[tid] = m;
    __syncthreads();
    if (r == 0) {
        float mtot = -INFINITY;
#pragma unroll
        for (int i = 0; i < 32; ++i) mtot = fmaxf(mtot, red[i * 32 + c]);
        gr[32 + c] = (cnt > 0) ? mtot : 0.f;
    }
    __syncthreads();
    if (tid < 32) {
        float acc = bm1[tid];
#pragma unroll
        for (int k = 0; k < 64; ++k) acc = fmaf(gr[k], Wm1[k * 32 + tid], acc);
        h[tid] = eluf(acc);
    }
    __syncthreads();
    if (tid < 2) {
        float acc = bm2[tid];
#pragma unroll
        for (int k = 0; k < 32; ++k) acc = fmaf(h[k], Wm2[k * 2 + tid], acc);
        out[g * 2 + tid] = acc;
    }
}

extern "C" void kernel_launch(void* const* d_in, const int* in_sizes, int n_in,
                              void* d_out, int out_size, void* d_ws, size_t ws_size,
                              hipStream_t stream) {
    const float* x    = (const float*)d_in[0];
    const int*   eidx = (const int*)d_in[1];
    const int*   src  = eidx;
    const int*   dst  = eidx + NE;
    const int*   batch = (const int*)d_in[3];
    const float* W1  = (const float*)d_in[4];
    const float* g1  = (const float*)d_in[6];
    const float* be1 = (const float*)d_in[7];
    const float* W2  = (const float*)d_in[8];
    const float* g2  = (const float*)d_in[10];
    const float* be2 = (const float*)d_in[11];
    const float* Wm1 = (const float*)d_in[12];
    const float* bm1 = (const float*)d_in[13];
    const float* Wm2 = (const float*)d_in[14];
    const float* bm2 = (const float*)d_in[15];
    float* out = (float*)d_out;

    // ---- workspace layout ----
    constexpr int CSRSZ = NBKT * PADREG + 16;     // fixed-stride padded csr (~10.8 MB)
    int*    bktCur  = (int*)d_ws;                 // 800 -- zeroed
    float*  S       = (float*)(bktCur + 800);     // 512 stat floats -- zeroed
    int*    gptr    = (int*)(S + 512);            // 544
    int*    csr     = gptr + 544;                 // CSRSZ (8-aligned rows)
    int2*   rowInfo = (int2*)(csr + CSRSZ);       // 100000
    float*  dinv    = (float*)(rowInfo + 100000); // 100000
    bf16_t* y1b     = (bf16_t*)(dinv + 100000);   // 4 slices x (NN+1)*16
    bf16_t* agg1b   = y1b + (NN + 1) * 64;        // 4 slices x NN*16
    bf16_t* y2b     = agg1b + NN * 64;            // 2 slices x (NN+1)*16
    bf16_t* agg2b   = y2b + (NN + 1) * 32;        // 2 slices x NN*16
    int*    ebuf    = (int*)y2b;                  // NBKT*BSTR ints (8 MB), aliases y2/agg2

    float* sum1 = S;        float* sq1 = S + 64;
    float* sum2 = S + 128;  float* sq2 = S + 160;

    // ---- init: bucket cursors + stats in one memset ----
    (void)hipMemsetAsync(bktCur, 0, (800 + 512) * sizeof(int), stream);

    // ---- edge bucketing (R17: 391 blocks, int4 quads, register-held) ----
    k_scatter_bkt<<<391, 1024, 0, stream>>>(src, dst, bktCur, ebuf);
    k_sort_gemm1<<<2 * NBKT + 1, 256, 0, stream>>>(bktCur, ebuf, csr, rowInfo, dinv,
                                                   batch, gptr, x, W1, y1b);

    // ---- layer 1 gather (R8 grid: 782 parts x 4 slices) ----
    k_gather<4><<<3128, 256, 0, stream>>>(rowInfo, csr, dinv,
                                          (const uint4*)y1b, (uint4*)agg1b,
                                          sum1, sq1);

    // ---- layer 2 (BN+ELU+stats fused into GEMM; y2 = dinv * h1W2, blocked) ----
    k_bn_gemm2<<<NN / 32 + 1, 256, 0, stream>>>((const unsigned*)agg1b, sum1, sq1,
                                                g1, be1, W2, dinv, y2b);
    k_gather<2><<<1564, 256, 0, stream>>>(rowInfo, csr, dinv,
                                          (const uint4*)y2b, (uint4*)agg2b,
                                          sum2, sq2);

    // ---- pooling + MLP head in one kernel (1024 threads) ----
    k_poolmlp<<<NG, 1024, 0, stream>>>((const unsigned*)agg2b, sum2, sq2, g2, be2, gptr,
                                       Wm1, bm1, Wm2, bm2, out);
}

// Round 19
// 255.181 us; speedup vs baseline: 1.2614x; 1.0021x over previous
//
#include <hip/hip_runtime.h>
#include <math.h>

constexpr int NN = 100000;
constexpr int NE = 1600000;
constexpr int NG = 512;
constexpr int NBKT = (NN + 127) / 128;   // 782 dst-buckets (128 nodes each)
constexpr int BSTR = 2560;               // fixed bucket capacity (mean 2048, sd 45 -> 11 sigma)
constexpr int PADREG = BSTR + 896;       // padded csr region per bucket
constexpr int BCAP = 3072;               // LDS staging capacity

typedef unsigned short bf16_t;
typedef unsigned int u32x4 __attribute__((ext_vector_type(4)));   // nontemporal-store-able
typedef int i32x4 __attribute__((ext_vector_type(4)));            // nontemporal-load-able
__device__ __forceinline__ bf16_t f2bf(float f) {
    unsigned u = __float_as_uint(f);
    unsigned r = (u + 0x7fffu + ((u >> 16) & 1u)) >> 16;   // round-nearest-even
    return (bf16_t)r;
}
__device__ __forceinline__ float bflo(unsigned u) { return __uint_as_float(u << 16); }
__device__ __forceinline__ float bfhi(unsigned u) { return __uint_as_float(u & 0xffff0000u); }
__device__ __forceinline__ unsigned bfpack(float lo, float hi) {
    return ((unsigned)f2bf(hi) << 16) | (unsigned)f2bf(lo);
}
__device__ __forceinline__ float eluf(float x) {
    return x > 0.f ? x : expm1f(x);
}

// LDS-aggregated bucket scatter (R17-verified): 391 blocks x 1024 threads,
// 4 edges/thread via int4 quads held in registers across both passes.
__global__ __launch_bounds__(1024) void k_scatter_bkt(const int* __restrict__ src,
                                                      const int* __restrict__ dst,
                                                      int* __restrict__ bktCur,
                                                      int* __restrict__ ebuf) {
    __shared__ int cnt[NBKT];
    __shared__ int base[NBKT];
    int tid = threadIdx.x;
    for (int i = tid; i < NBKT; i += 1024) cnt[i] = 0;
    __syncthreads();
    int e0 = blockIdx.x * 4096;
    int e1 = min(e0 + 4096, NE);
    int e = e0 + tid * 4;
    bool act = (e + 4 <= e1);
    i32x4 sv, dv;
    sv.x = 0; sv.y = 0; sv.z = 0; sv.w = 0;
    dv = sv;
    if (act) {
        sv = __builtin_nontemporal_load((const i32x4*)(src + e));
        dv = __builtin_nontemporal_load((const i32x4*)(dst + e));
        atomicAdd(&cnt[dv.x >> 7], 1);
        atomicAdd(&cnt[dv.y >> 7], 1);
        atomicAdd(&cnt[dv.z >> 7], 1);
        atomicAdd(&cnt[dv.w >> 7], 1);
    }
    __syncthreads();
    for (int i = tid; i < NBKT; i += 1024) {
        int c = cnt[i];
        base[i] = i * BSTR + (c ? atomicAdd(&bktCur[i], c) : 0);
        cnt[i] = 0;                 // reuse as local cursor
    }
    __syncthreads();
    if (act) {
        int b, off;
        b = dv.x >> 7; off = atomicAdd(&cnt[b], 1); ebuf[base[b] + off] = (sv.x << 7) | (dv.x & 127);
        b = dv.y >> 7; off = atomicAdd(&cnt[b], 1); ebuf[base[b] + off] = (sv.y << 7) | (dv.y & 127);
        b = dv.z >> 7; off = atomicAdd(&cnt[b], 1); ebuf[base[b] + off] = (sv.z << 7) | (dv.z & 127);
        b = dv.w >> 7; off = atomicAdd(&cnt[b], 1); ebuf[base[b] + off] = (sv.w << 7) | (dv.w & 127);
    }
}

// FUSED heterogeneous kernel (R16-verified): blocks [0,NBKT): gemm1 role
// (one block per bucket, 2 tiles, single bucket scan for degrees);
// [NBKT,2*NBKT): bktsort; 2*NBKT: gptr.
__global__ __launch_bounds__(256) void k_sort_gemm1(const int* __restrict__ bktCur,
                                                    const int* __restrict__ ebuf,
                                                    int* __restrict__ csr,
                                                    int2* __restrict__ rowInfo,
                                                    float* __restrict__ dinv,
                                                    const int* __restrict__ batch,
                                                    int* __restrict__ gptr,
                                                    const float* __restrict__ x,
                                                    const float* __restrict__ W1,
                                                    bf16_t* __restrict__ y1b) {
    __shared__ __align__(16) unsigned smem_u[8704];   // 34.8 KB union
    int tid = threadIdx.x;
    if (blockIdx.x < NBKT) {
        // ---------------- gemm1 role: bucket blockIdx.x, 2 tiles ----------------
        float* sx = (float*)smem_u;                   // [64*68]
        float* sw = sx + 64 * 68;                     // [66*64]
        int*  deg = (int*)(sw + 66 * 64);             // [128]
        if (tid < 128) deg[tid] = 0;
        for (int i = tid; i < 66 * 32; i += 256) ((float2*)sw)[i] = ((const float2*)W1)[i];
        int bkt = blockIdx.x;
        int base0 = bkt * 128;
        // single bucket scan -> 128-node degree histogram
        int ne = min(bktCur[bkt], BSTR);
        for (int i = tid; i < ne; i += 256)
            atomicAdd(&deg[ebuf[bkt * BSTR + i] & 127], 1);
#pragma unroll
        for (int t = 0; t < 2; ++t) {
            int tbase = base0 + t * 64;
            if (tbase > NN) break;                    // beyond sentinel: nothing to do
            int rows = min(64, NN - tbase);           // valid x rows
            if (t == 1) __syncthreads();              // sx reuse: wait for tile-A reads
            if (rows > 0) {
                int cnt2v = rows * 33;
                const float2* xp = (const float2*)(x + (size_t)tbase * 66);
                for (int i = tid; i < cnt2v; i += 256) {
                    int r = i / 33, kk = i - r * 33;
                    ((float2*)(sx + r * 68))[kk] = xp[i];
                }
            }
            __syncthreads();                          // sx + sw + deg ready
            int tr = tid >> 4, tc = tid & 15;         // 16 row-groups x 16 col-groups
            const float* sxr = sx + tr * 4 * 68;
            const float* swc = sw + tc * 4;
            float acc[4][4];
#pragma unroll
            for (int r = 0; r < 4; ++r)
#pragma unroll
                for (int c = 0; c < 4; ++c) acc[r][c] = 0.f;
#pragma unroll 4
            for (int ks = 0; ks < 64; ks += 4) {
                float4 a0 = *(const float4*)(sxr + 0 * 68 + ks);
                float4 a1 = *(const float4*)(sxr + 1 * 68 + ks);
                float4 a2 = *(const float4*)(sxr + 2 * 68 + ks);
                float4 a3 = *(const float4*)(sxr + 3 * 68 + ks);
                float4 b0 = *(const float4*)(swc + (ks + 0) * 64);
                float4 b1 = *(const float4*)(swc + (ks + 1) * 64);
                float4 b2 = *(const float4*)(swc + (ks + 2) * 64);
                float4 b3 = *(const float4*)(swc + (ks + 3) * 64);
#define FMA4(ar, bv) do { \
                acc[0][0] = fmaf(a0.ar, bv.x, acc[0][0]); acc[0][1] = fmaf(a0.ar, bv.y, acc[0][1]); \
                acc[0][2] = fmaf(a0.ar, bv.z, acc[0][2]); acc[0][3] = fmaf(a0.ar, bv.w, acc[0][3]); \
                acc[1][0] = fmaf(a1.ar, bv.x, acc[1][0]); acc[1][1] = fmaf(a1.ar, bv.y, acc[1][1]); \
                acc[1][2] = fmaf(a1.ar, bv.z, acc[1][2]); acc[1][3] = fmaf(a1.ar, bv.w, acc[1][3]); \
                acc[2][0] = fmaf(a2.ar, bv.x, acc[2][0]); acc[2][1] = fmaf(a2.ar, bv.y, acc[2][1]); \
                acc[2][2] = fmaf(a2.ar, bv.z, acc[2][2]); acc[2][3] = fmaf(a2.ar, bv.w, acc[2][3]); \
                acc[3][0] = fmaf(a3.ar, bv.x, acc[3][0]); acc[3][1] = fmaf(a3.ar, bv.y, acc[3][1]); \
                acc[3][2] = fmaf(a3.ar, bv.z, acc[3][2]); acc[3][3] = fmaf(a3.ar, bv.w, acc[3][3]); } while (0)
                FMA4(x, b0); FMA4(y, b1); FMA4(z, b2); FMA4(w, b3);
#undef FMA4
            }
            // k tail: 64, 65
#pragma unroll
            for (int k = 64; k < 66; ++k) {
                float4 bt = *(const float4*)(swc + k * 64);
#pragma unroll
                for (int r = 0; r < 4; ++r) {
                    float av = sxr[r * 68 + k];
                    acc[r][0] = fmaf(av, bt.x, acc[r][0]);
                    acc[r][1] = fmaf(av, bt.y, acc[r][1]);
                    acc[r][2] = fmaf(av, bt.z, acc[r][2]);
                    acc[r][3] = fmaf(av, bt.w, acc[r][3]);
                }
            }
            // epilogue: cols tc*4..tc*4+3 in slice tc>>2, lanes (tc&3)*4..+3
            bf16_t* dstp = y1b + (tc >> 2) * ((NN + 1) * 16) + (tc & 3) * 4;
#pragma unroll
            for (int r = 0; r < 4; ++r) {
                int nn = tbase + tr * 4 + r;
                if (nn < NN) {
                    float di = rsqrtf((float)deg[t * 64 + tr * 4 + r] + 1.0f);
                    ushort4 o;
                    o.x = f2bf(di * acc[r][0]); o.y = f2bf(di * acc[r][1]);
                    o.z = f2bf(di * acc[r][2]); o.w = f2bf(di * acc[r][3]);
                    *(ushort4*)(dstp + (size_t)nn * 16) = o;
                } else if (nn == NN) {
                    ushort4 o; o.x = 0; o.y = 0; o.z = 0; o.w = 0;
                    *(ushort4*)(dstp + (size_t)nn * 16) = o;   // sentinel zero row
                }
            }
        }
        return;
    }
    // ---------------- bktsort role (R8-verified) ----------------
    int b = blockIdx.x - NBKT;
    if (b == NBKT) {                                  // gptr block
        for (int g = tid; g <= NG; g += 256) {
            if (g == NG) { gptr[NG] = NN; continue; }
            int lo = 0, hi = NN;
            while (lo < hi) {
                int mid = (lo + hi) >> 1;
                if (batch[mid] < g) lo = mid + 1; else hi = mid;
            }
            gptr[g] = lo;
        }
        return;
    }
    int* sbuf = (int*)smem_u;                         // [BCAP]
    int* cnt  = sbuf + BCAP;                          // [128]
    int* scn  = cnt + 128;                            // [128]
    int* cur  = scn + 128;                            // [128]
    int* padTotS = cur + 128;                         // [1]
    int base = b * BSTR;
    int n = min(bktCur[b], BSTR);
    int pbase = b * PADREG;                           // 8-aligned (PADREG % 8 == 0)
    for (int i = tid; i < n; i += 256) sbuf[i] = __builtin_nontemporal_load(ebuf + base + i);
    if (tid < 128) cnt[tid] = 0;
    __syncthreads();
    for (int i = tid; i < n; i += 256) atomicAdd(&cnt[sbuf[i] & 127], 1);
    __syncthreads();
    int deg = (tid < 128) ? cnt[tid] : 0;
    int pcnt = (deg + 7) & ~7;
    if (tid < 128) scn[tid] = pcnt;
    __syncthreads();
    for (int off = 1; off < 128; off <<= 1) {
        int t = (tid < 128 && tid >= off) ? scn[tid - off] : 0;
        __syncthreads();
        if (tid < 128) scn[tid] += t;
        __syncthreads();
    }
    if (tid == 127) *padTotS = scn[127];
    if (tid < 128) {
        int ex = scn[tid] - pcnt;
        cur[tid] = ex;
        int node = b * 128 + tid;
        if (node < NN) {
            rowInfo[node] = make_int2(pbase + ex, pbase + ex + pcnt);
            dinv[node] = rsqrtf((float)deg + 1.0f);
        }
    }
    __syncthreads();
    int padTot = *padTotS;
    for (int i = tid; i < padTot; i += 256) csr[pbase + i] = NN;   // sentinel fill
    __syncthreads();
    for (int i = tid; i < n; i += 256) {
        int p = sbuf[i];
        int pos = atomicAdd(&cur[p & 127], 1);
        csr[pbase + pos] = p >> 7;
    }
}

// Slice-blocked CSR gather (R8-verified form). 32B rows, 4 slices L2-fit;
// 2-lane groups, 16B uint4 per lane; csr cacheable + one-round-ahead
// prefetch younger than y loads.
template<int NSL>   // 4 for C=64, 2 for C=32
__global__ __launch_bounds__(256) void k_gather(const int2* __restrict__ rowInfo,
                                                const int* __restrict__ csr,
                                                const float* __restrict__ dinv,
                                                const uint4* __restrict__ yb,
                                                uint4* __restrict__ aggb,
                                                float* __restrict__ sums,
                                                float* __restrict__ sqs) {
    constexpr int SH = (NSL == 4) ? 2 : 1;
    __shared__ float sSum[16], sSq[16];
    int tid = threadIdx.x;
    if (tid < 16) { sSum[tid] = 0.f; sSq[tid] = 0.f; }
    __syncthreads();
    int slice = blockIdx.x & (NSL - 1);
    int part = blockIdx.x >> SH;
    int nparts = gridDim.x >> SH;
    int lane = tid & 1;                           // half-row selector
    int grp = tid >> 1;                           // 128 node-groups per block
    const uint4* y = yb + (size_t)slice * ((NN + 1) * 2) + lane;
    uint4* agg = aggb + (size_t)slice * (NN * 2) + lane;
    float s[8], q[8];
#pragma unroll
    for (int k = 0; k < 8; ++k) { s[k] = 0.f; q[k] = 0.f; }
    for (int n = part * 128 + grp; n < NN; n += nparts * 128) {
        int2 ri = rowInfo[n];
        float a[8];
#pragma unroll
        for (int k = 0; k < 8; ++k) a[k] = 0.f;
        int j = ri.x;
        unsigned long long c0 = 0, c1 = 0, c2 = 0, c3 = 0;
        if (j < ri.y) {                            // prime the csr pipeline
            const unsigned long long* cp = (const unsigned long long*)(csr + j);
            c0 = cp[0]; c1 = cp[1]; c2 = cp[2]; c3 = cp[3];
        }
        while (j < ri.y) {
            int i0 = (int)(c0 & 0xffffffffu), i1 = (int)(c0 >> 32);
            int i2 = (int)(c1 & 0xffffffffu), i3 = (int)(c1 >> 32);
            int i4 = (int)(c2 & 0xffffffffu), i5 = (int)(c2 >> 32);
            int i6 = (int)(c3 & 0xffffffffu), i7 = (int)(c3 >> 32);
            j += 8;
            uint4 v0 = y[i0 * 2];
            uint4 v1 = y[i1 * 2];
            uint4 v2 = y[i2 * 2];
            uint4 v3 = y[i3 * 2];
            uint4 v4 = y[i4 * 2];
            uint4 v5 = y[i5 * 2];
            uint4 v6 = y[i6 * 2];
            uint4 v7 = y[i7 * 2];
            if (j < ri.y) {                        // prefetch next round (younger than y)
                const unsigned long long* np = (const unsigned long long*)(csr + j);
                c0 = np[0]; c1 = np[1]; c2 = np[2]; c3 = np[3];
            }
#define ACC8(v) do { \
            a[0] += bflo((v).x); a[1] += bfhi((v).x); \
            a[2] += bflo((v).y); a[3] += bfhi((v).y); \
            a[4] += bflo((v).z); a[5] += bfhi((v).z); \
            a[6] += bflo((v).w); a[7] += bfhi((v).w); } while (0)
            ACC8(v0); ACC8(v1); ACC8(v2); ACC8(v3);
            ACC8(v4); ACC8(v5); ACC8(v6); ACC8(v7);
#undef ACC8
        }
        uint4 vs = y[n * 2];                      // self loop
        float di = dinv[n];
        a[0] = di * (a[0] + bflo(vs.x)); a[1] = di * (a[1] + bfhi(vs.x));
        a[2] = di * (a[2] + bflo(vs.y)); a[3] = di * (a[3] + bfhi(vs.y));
        a[4] = di * (a[4] + bflo(vs.z)); a[5] = di * (a[5] + bfhi(vs.z));
        a[6] = di * (a[6] + bflo(vs.w)); a[7] = di * (a[7] + bfhi(vs.w));
        u32x4 o;
        o.x = bfpack(a[0], a[1]); o.y = bfpack(a[2], a[3]);
        o.z = bfpack(a[4], a[5]); o.w = bfpack(a[6], a[7]);
        __builtin_nontemporal_store(o, (u32x4*)(agg + n * 2));
#pragma unroll
        for (int k = 0; k < 8; ++k) {
            float av = (k == 0) ? a[0] : (k == 1) ? a[1] : (k == 2) ? a[2] : (k == 3) ? a[3]
                     : (k == 4) ? a[4] : (k == 5) ? a[5] : (k == 6) ? a[6] : a[7];
            s[k] += av; q[k] += av * av;
        }
    }
    // wave shuffle-tree over the 32 group-pairs (keeps lane parity separate),
    // then 2 threads/wave commit to LDS (64 LDS atomics/block, was 2048).
#pragma unroll
    for (int k = 0; k < 8; ++k) {
        float sv = s[k], qv = q[k];
#pragma unroll
        for (int off = 2; off < 64; off <<= 1) {
            sv += __shfl_xor(sv, off);
            qv += __shfl_xor(qv, off);
        }
        if ((tid & 63) < 2) {
            atomicAdd(&sSum[lane * 8 + k], sv);
            atomicAdd(&sSq[lane * 8 + k], qv);
        }
    }
    __syncthreads();
    if (tid < 16) {
        unsafeAtomicAdd(&sums[slice * 16 + tid], sSum[tid]);
        unsafeAtomicAdd(&sqs[slice * 16 + tid], sSq[tid]);
    }
}

// fused: scale/shift from sums/sqs, h1 = elu(bn(agg1)) in LDS, y2 = dinv*(h1@W2).
// R11-verified: 32 rows/block, sW transposed (pad 68), float4 LDS reads.
__global__ void k_bn_gemm2(const unsigned* __restrict__ agg1b, const float* __restrict__ sums,
                           const float* __restrict__ sqs, const float* __restrict__ gamma,
                           const float* __restrict__ beta, const float* __restrict__ W2,
                           const float* __restrict__ dinv, bf16_t* __restrict__ y2b) {
    constexpr int RB = 32;
    __shared__ __align__(16) float sh[RB * 64];
    __shared__ __align__(16) float sWt[32 * 68];   // sWt[c*68+k] = W2[k*32+c]
    __shared__ float sscale[64], sshift[64];
    int tid = threadIdx.x;
    if (tid < 64) {
        float mu = sums[tid] * (1.0f / NN);
        float var = sqs[tid] * (1.0f / NN) - mu * mu;
        float sc = gamma[tid] * rsqrtf(var + 1e-5f);
        sscale[tid] = sc;
        sshift[tid] = beta[tid] - mu * sc;
    }
#pragma unroll
    for (int i = tid; i < 64 * 32; i += 256) {
        int k = i >> 5, c = i & 31;
        sWt[c * 68 + k] = W2[i];
    }
    __syncthreads();
    int base = blockIdx.x * RB;
#pragma unroll
    for (int rr = 0; rr < RB / 8; ++rr) {
        int r = (tid >> 5) + rr * 8, qq = tid & 31;
        int slice = qq >> 3, lane = qq & 7;
        int n = base + r;
        int col = slice * 16 + lane * 2;
        float v0 = 0.f, v1 = 0.f;
        if (n < NN) {
            unsigned u = agg1b[(size_t)slice * NN * 8 + (size_t)n * 8 + lane];
            v0 = eluf(fmaf(bflo(u), sscale[col], sshift[col]));
            v1 = eluf(fmaf(bfhi(u), sscale[col + 1], sshift[col + 1]));
        }
        sh[r * 64 + col] = v0;
        sh[r * 64 + col + 1] = v1;
    }
    __syncthreads();
    int c = tid & 31;
    bf16_t* dstp = y2b + (c >> 4) * ((NN + 1) * 16) + (c & 15);
    const float* swr = sWt + c * 68;
#pragma unroll
    for (int rr = 0; rr < RB / 8; ++rr) {
        int r = (tid >> 5) + rr * 8;
        int n = base + r;
        if (n < NN) {
            const float* shr = sh + r * 64;
            float acc = 0.f;
#pragma unroll
            for (int k4 = 0; k4 < 64; k4 += 4) {
                float4 av = *(const float4*)(shr + k4);
                float4 bv = *(const float4*)(swr + k4);
                acc = fmaf(av.x, bv.x, acc);
                acc = fmaf(av.y, bv.y, acc);
                acc = fmaf(av.z, bv.z, acc);
                acc = fmaf(av.w, bv.w, acc);
            }
            dstp[(size_t)n * 16] = f2bf(dinv[n] * acc);
        } else if (n == NN) {
            dstp[(size_t)NN * 16] = 0;            // sentinel zero row
        }
    }
}

// fused: BN stats -> scale/shift, segment pool (no atomics), 2-layer MLP head.
// R15-verified: 1024 threads/block -> 32 waves/CU occupancy cap.
__global__ __launch_bounds__(1024) void k_poolmlp(const unsigned* __restrict__ agg2b,
                          const float* __restrict__ sums,
                          const float* __restrict__ sqs, const float* __restrict__ gamma,
                          const float* __restrict__ beta, const int* __restrict__ gptr,
                          const float* __restrict__ Wm1, const float* __restrict__ bm1,
                          const float* __restrict__ Wm2, const float* __restrict__ bm2,
                          float* __restrict__ out) {
    __shared__ float sscale[32], sshift[32];
    __shared__ float red[1024];
    __shared__ float gr[64];
    __shared__ float h[32];
    int tid = threadIdx.x;
    if (tid < 32) {
        float mu = sums[tid] * (1.0f / NN);
        float var = sqs[tid] * (1.0f / NN) - mu * mu;
        float sc = gamma[tid] * rsqrtf(var + 1e-5f);
        sscale[tid] = sc;
        sshift[tid] = beta[tid] - mu * sc;
    }
    __syncthreads();
    int g = blockIdx.x;
    int c = tid & 31, r = tid >> 5;               // r in [0,32)
    int beg = gptr[g], end = gptr[g + 1];
    float scl = sscale[c], shf = sshift[c];
    const unsigned* ap = agg2b + (size_t)(c >> 4) * NN * 8 + ((c >> 1) & 7);
    bool hi = (c & 1);
    float s = 0.f, m = -INFINITY;
    for (int n = beg + r; n < end; n += 32) {
        unsigned u = ap[n * 8];
        float v = eluf(fmaf(hi ? bfhi(u) : bflo(u), scl, shf));
        s += v;
        m = fmaxf(m, v);
    }
    red[tid] = s;
    __syncthreads();
    int cnt = end - beg;
    if (r == 0) {
        float stot = 0.f;
#pragma unroll
        for (int i = 0; i < 32; ++i) stot += red[i * 32 + c];
        gr[c] = stot / fmaxf((float)cnt, 1.f);
    }
    __syncthreads();
    red[tid] = m;
    __syncthreads();
    if (r == 0) {
        float mtot = -INFINITY;
#pragma unroll
        for (int i = 0; i < 32; ++i) mtot = fmaxf(mtot, red[i * 32 + c]);
        gr[32 + c] = (cnt > 0) ? mtot : 0.f;
    }
    __syncthreads();
    if (tid < 32) {
        float acc = bm1[tid];
#pragma unroll
        for (int k = 0; k < 64; ++k) acc = fmaf(gr[k], Wm1[k * 32 + tid], acc);
        h[tid] = eluf(acc);
    }
    __syncthreads();
    if (tid < 2) {
        float acc = bm2[tid];
#pragma unroll
        for (int k = 0; k < 32; ++k) acc = fmaf(h[k], Wm2[k * 2 + tid], acc);
        out[g * 2 + tid] = acc;
    }
}

extern "C" void kernel_launch(void* const* d_in, const int* in_sizes, int n_in,
                              void* d_out, int out_size, void* d_ws, size_t ws_size,
                              hipStream_t stream) {
    const float* x    = (const float*)d_in[0];
    const int*   eidx = (const int*)d_in[1];
    const int*   src  = eidx;
    const int*   dst  = eidx + NE;
    const int*   batch = (const int*)d_in[3];
    const float* W1  = (const float*)d_in[4];
    const float* g1  = (const float*)d_in[6];
    const float* be1 = (const float*)d_in[7];
    const float* W2  = (const float*)d_in[8];
    const float* g2  = (const float*)d_in[10];
    const float* be2 = (const float*)d_in[11];
    const float* Wm1 = (const float*)d_in[12];
    const float* bm1 = (const float*)d_in[13];
    const float* Wm2 = (const float*)d_in[14];
    const float* bm2 = (const float*)d_in[15];
    float* out = (float*)d_out;

    // ---- workspace layout ----
    constexpr int CSRSZ = NBKT * PADREG + 16;     // fixed-stride padded csr (~10.8 MB)
    int*    bktCur  = (int*)d_ws;                 // 800 -- zeroed
    float*  S       = (float*)(bktCur + 800);     // 512 stat floats -- zeroed
    int*    gptr    = (int*)(S + 512);            // 544
    int*    csr     = gptr + 544;                 // CSRSZ (8-aligned rows)
    int2*   rowInfo = (int2*)(csr + CSRSZ);       // 100000
    float*  dinv    = (float*)(rowInfo + 100000); // 100000
    bf16_t* y1b     = (bf16_t*)(dinv + 100000);   // 4 slices x (NN+1)*16
    bf16_t* agg1b   = y1b + (NN + 1) * 64;        // 4 slices x NN*16
    bf16_t* y2b     = agg1b + NN * 64;            // 2 slices x (NN+1)*16
    bf16_t* agg2b   = y2b + (NN + 1) * 32;        // 2 slices x NN*16
    int*    ebuf    = (int*)y2b;                  // NBKT*BSTR ints (8 MB), aliases y2/agg2

    float* sum1 = S;        float* sq1 = S + 64;
    float* sum2 = S + 128;  float* sq2 = S + 160;

    // ---- init: bucket cursors + stats in one memset ----
    (void)hipMemsetAsync(bktCur, 0, (800 + 512) * sizeof(int), stream);

    // ---- edge bucketing (R17: 391 blocks, int4 quads, register-held) ----
    k_scatter_bkt<<<391, 1024, 0, stream>>>(src, dst, bktCur, ebuf);
    k_sort_gemm1<<<2 * NBKT + 1, 256, 0, stream>>>(bktCur, ebuf, csr, rowInfo, dinv,
                                                   batch, gptr, x, W1, y1b);

    // ---- layer 1 gather (R8 grid: 782 parts x 4 slices) ----
    k_gather<4><<<3128, 256, 0, stream>>>(rowInfo, csr, dinv,
                                          (const uint4*)y1b, (uint4*)agg1b,
                                          sum1, sq1);

    // ---- layer 2 (BN+ELU+stats fused into GEMM; y2 = dinv * h1W2, blocked) ----
    k_bn_gemm2<<<NN / 32 + 1, 256, 0, stream>>>((const unsigned*)agg1b, sum1, sq1,
                                                g1, be1, W2, dinv, y2b);
    k_gather<2><<<1564, 256, 0, stream>>>(rowInfo, csr, dinv,
                                          (const uint4*)y2b, (uint4*)agg2b,
                                          sum2, sq2);

    // ---- pooling + MLP head in one kernel (1024 threads) ----
    k_poolmlp<<<NG, 1024, 0, stream>>>((const unsigned*)agg2b, sum2, sq2, g2, be2, gptr,
                                       Wm1, bm1, Wm2, bm2, out);
}